// Round 8
// baseline (1644.712 us; speedup 1.0000x reference)
//
#include <hip/hip_runtime.h>

using u16 = unsigned short;

__device__ __forceinline__ float bf2f(u16 u) {
  return __uint_as_float(((unsigned int)u) << 16);
}
__device__ __forceinline__ u16 f2bf(float f) {
  unsigned int u = __float_as_uint(f);
  unsigned int r = u + 0x7FFFu + ((u >> 16) & 1u);
  return (u16)(r >> 16);
}

// ---------------- K0: transpose pam_v_w [c][ci] -> wvT [ci][c] ---------------
__global__ void k_prep_wv(const float* __restrict__ wv, float* __restrict__ wvT) {
  int idx = blockIdx.x * 256 + threadIdx.x;   // 16384
  int ci = idx >> 7, c = idx & 127;
  wvT[ci * 128 + c] = wv[c * 128 + ci];
}

// ---------------- K1: BN+ReLU for both branches, f32 out ---------------------
__global__ void k_bnrelu2(const float* __restrict__ x,
    const float* __restrict__ wa, const float* __restrict__ ba,
    const float* __restrict__ ma, const float* __restrict__ va,
    const float* __restrict__ wc, const float* __restrict__ bc,
    const float* __restrict__ mc, const float* __restrict__ vc,
    float* __restrict__ xa, float* __restrict__ xcb) {
  int i4 = (blockIdx.x * 256 + threadIdx.x) * 4;   // over 2*512*4096
  int c = (i4 >> 12) & 511;
  float sA = wa[c] * rsqrtf(va[c] + 1e-5f);
  float bA = ba[c] - ma[c] * sA;
  float sC = wc[c] * rsqrtf(vc[c] + 1e-5f);
  float bC = bc[c] - mc[c] * sC;
  float4 xv = *(const float4*)(x + i4);
  float4 oa, oc;
  oa.x = fmaxf(xv.x * sA + bA, 0.f); oc.x = fmaxf(xv.x * sC + bC, 0.f);
  oa.y = fmaxf(xv.y * sA + bA, 0.f); oc.y = fmaxf(xv.y * sC + bC, 0.f);
  oa.z = fmaxf(xv.z * sA + bA, 0.f); oc.z = fmaxf(xv.z * sC + bC, 0.f);
  oa.w = fmaxf(xv.w * sA + bA, 0.f); oc.w = fmaxf(xv.w * sC + bC, 0.f);
  *(float4*)(xa + i4) = oa;
  *(float4*)(xcb + i4) = oc;
}

// ---------------- K2: 3x3 conv SAME 512->128, co-tile 4, 2048 blocks ---------
// block: 256 thr = 4 rows x 64 cols; computes 4 co for that tile.
// grid: (16 h-groups, 32 co-groups, 4: z = b + 2*branch) -> 8 blocks/CU
__global__ __launch_bounds__(256) void k_conv3t(
    const float* __restrict__ xa, const float* __restrict__ xcb,
    const float* __restrict__ wa, const float* __restrict__ wc,
    float* __restrict__ sa0, float* __restrict__ sc0) {
  __shared__ float ls[8 * 396];   // 8 ci x 6 rows x 66 (w-halo), zero-padded
  int t = threadIdx.x;
  int hg = blockIdx.x, cg = blockIdx.y, z = blockIdx.z;
  int b = z & 1, br = z >> 1;
  const float* xin = br ? xcb : xa;
  const float* wconv = br ? wc : wa;
  float* out = br ? sc0 : sa0;
  int h0 = hg * 4;
  int w = t & 63, hl = t >> 6;
  int co0 = cg * 4;
  float acc[4] = {};
  const float* xb = xin + ((size_t)b * 512 << 12);
  for (int ci0 = 0; ci0 < 512; ci0 += 8) {
    __syncthreads();
    for (int idx = t; idx < 3168; idx += 256) {
      int ci_l = idx / 396;
      int rem = idx - ci_l * 396;
      int row = rem / 66;
      int w66 = rem - row * 66;
      int gh = h0 - 1 + row;
      int gw = w66 - 1;
      float v = 0.f;
      if (gh >= 0 && gh < 64 && gw >= 0 && gw < 64)
        v = xb[((size_t)(ci0 + ci_l) << 12) + (gh << 6) + gw];
      ls[idx] = v;
    }
    __syncthreads();
    for (int ci_l = 0; ci_l < 8; ++ci_l) {
      const float* c = ls + ci_l * 396 + (hl + 1) * 66 + (w + 1);
      float x00 = c[-67], x01 = c[-66], x02 = c[-65];
      float x10 = c[-1],  x11 = c[0],   x12 = c[1];
      float x20 = c[65],  x21 = c[66],  x22 = c[67];
      const float* wp = wconv + (size_t)co0 * 4608 + (ci0 + ci_l) * 9;
#pragma unroll
      for (int co = 0; co < 4; ++co) {
        const float* wq = wp + co * 4608;   // block-uniform -> scalar loads
        acc[co] = fmaf(wq[0], x00, fmaf(wq[1], x01, fmaf(wq[2], x02,
                  fmaf(wq[3], x10, fmaf(wq[4], x11, fmaf(wq[5], x12,
                  fmaf(wq[6], x20, fmaf(wq[7], x21, fmaf(wq[8], x22, acc[co])))))))));
      }
    }
  }
  int hw = ((h0 + hl) << 6) + w;
#pragma unroll
  for (int co = 0; co < 4; ++co)
    out[((size_t)(b * 128 + co0 + co) << 12) + hw] = acc[co];
}

// ---------------- K3a: 1x1 conv -> q,k ([b][16][4096] f32) -------------------
__global__ void k_qk(const float* __restrict__ sa0,
    const float* __restrict__ wq, const float* __restrict__ bq,
    const float* __restrict__ wk, const float* __restrict__ bk,
    float* __restrict__ qb, float* __restrict__ kb) {
  int n = blockIdx.x * 256 + threadIdx.x;
  int co = blockIdx.y, b = blockIdx.z;
  const float* w; float* dst; float bias;
  if (co < 16) { w = wq + co * 128; bias = bq[co]; dst = qb + ((b * 16 + co) << 12); }
  else { int c2 = co - 16; w = wk + c2 * 128; bias = bk[c2]; dst = kb + ((b * 16 + c2) << 12); }
  const float* s = sa0 + ((size_t)b * 128 << 12) + n;
  float acc = bias;
  for (int ci = 0; ci < 128; ++ci) acc = fmaf(w[ci], s[ci << 12], acc);
  dst[n] = acc;
}

// ---------------- K3b: 1x1 conv -> v, stored transposed vt[b][n][c] ----------
__global__ void k_vt(const float* __restrict__ sa0, const float* __restrict__ wvT,
                     const float* __restrict__ bv, float* __restrict__ vt) {
  int t = threadIdx.x;
  int c = t & 127, nh = t >> 7;
  int n = blockIdx.x * 2 + nh, b = blockIdx.y;
  const float* s = sa0 + ((size_t)b * 128 << 12) + n;
  float acc = bv[c];
  for (int ci = 0; ci < 128; ++ci) acc = fmaf(wvT[ci * 128 + c], s[ci << 12], acc);
  vt[((size_t)(b * 4096 + n)) * 128 + c] = acc;
}

// ---------------- K4: PAM softmax row stats (max, 1/sum) ---------------------
__global__ __launch_bounds__(256) void k_pam_stats(const float* __restrict__ qb,
    const float* __restrict__ kb, float* __restrict__ rmax, float* __restrict__ rinv) {
  int t = threadIdx.x, lane = t & 63, wid = t >> 6;
  int b = blockIdx.y;
  int n = blockIdx.x * 4 + wid;
  float qreg[16];
  const float* qp = qb + ((size_t)b * 16 << 12) + n;
#pragma unroll
  for (int ch = 0; ch < 16; ++ch) qreg[ch] = qp[ch << 12];
  const float* kp = kb + ((size_t)b * 16 << 12);
  float mx = -1e30f, se = 0.f;
  for (int m = lane; m < 4096; m += 64) {
    float e = 0.f;
#pragma unroll
    for (int ch = 0; ch < 16; ++ch) e = fmaf(qreg[ch], kp[(ch << 12) + m], e);
    float nm = fmaxf(mx, e);
    se = se * __expf(mx - nm) + __expf(e - nm);
    mx = nm;
  }
#pragma unroll
  for (int off = 32; off >= 1; off >>= 1) {
    float om = __shfl_xor(mx, off);
    float os = __shfl_xor(se, off);
    float nm = fmaxf(mx, om);
    se = se * __expf(mx - nm) + os * __expf(om - nm);
    mx = nm;
  }
  if (lane == 0) { rmax[(b << 12) + n] = mx; rinv[(b << 12) + n] = 1.f / se; }
}

// ---------------- K5: PAM PV, 16-n tile per block, 512 blocks ----------------
__global__ __launch_bounds__(256) void k_pam_pv(const float* __restrict__ qb,
    const float* __restrict__ kb, const float* __restrict__ vt,
    const float* __restrict__ rmax, const float* __restrict__ rinv,
    const float* __restrict__ sa0, const float* __restrict__ gamma,
    float* __restrict__ sa1) {
  __shared__ float qs[256];        // [ch][16 n]
  __shared__ float ks[1024];       // [ch][64 m]
  __shared__ float pbs[1024];      // [64 m][16 n]
  __shared__ float mxs[16], invs[16];
  __shared__ float obuf[128 * 17];
  int t = threadIdx.x;
  int b = blockIdx.y, n0 = blockIdx.x * 16;
  {
    int ch = t >> 4, r = t & 15;
    qs[t] = qb[((b * 16 + ch) << 12) + n0 + r];
  }
  if (t < 16) { mxs[t] = rmax[(b << 12) + n0 + t]; invs[t] = rinv[(b << 12) + n0 + t]; }
  int cp = t & 63, qd = t >> 6;
  float acc[4][2] = {};
  const float* kpb = kb + ((size_t)b * 16 << 12);
  for (int m0 = 0; m0 < 4096; m0 += 64) {
    for (int idx = t; idx < 1024; idx += 256) {
      int ch = idx >> 6, mm = idx & 63;
      ks[idx] = kpb[(ch << 12) + m0 + mm];
    }
    __syncthreads();
    {
      int m = t >> 2, r0 = (t & 3) * 4;
      float e0 = 0.f, e1 = 0.f, e2 = 0.f, e3 = 0.f;
#pragma unroll
      for (int ch = 0; ch < 16; ++ch) {
        float kk = ks[(ch << 6) + m];
        float4 qv = *(const float4*)(qs + (ch << 4) + r0);
        e0 = fmaf(kk, qv.x, e0); e1 = fmaf(kk, qv.y, e1);
        e2 = fmaf(kk, qv.z, e2); e3 = fmaf(kk, qv.w, e3);
      }
      float4 mv = *(const float4*)(mxs + r0);
      float4 iv = *(const float4*)(invs + r0);
      float4 pv;
      pv.x = __expf(fminf(e0 - mv.x, 0.f)) * iv.x;
      pv.y = __expf(fminf(e1 - mv.y, 0.f)) * iv.y;
      pv.z = __expf(fminf(e2 - mv.z, 0.f)) * iv.z;
      pv.w = __expf(fminf(e3 - mv.w, 0.f)) * iv.w;
      *(float4*)(pbs + (m << 4) + r0) = pv;
    }
    __syncthreads();
    const float* vp = vt + ((size_t)(b * 4096 + m0)) * 128 + (cp << 1);
#pragma unroll 4
    for (int mm = 0; mm < 64; ++mm) {
      float2 vv = *(const float2*)(vp + mm * 128);
      const float* pp = pbs + (mm << 4) + (qd << 2);
      float4 pA = *(const float4*)pp;
      acc[0][0] = fmaf(pA.x, vv.x, acc[0][0]); acc[0][1] = fmaf(pA.x, vv.y, acc[0][1]);
      acc[1][0] = fmaf(pA.y, vv.x, acc[1][0]); acc[1][1] = fmaf(pA.y, vv.y, acc[1][1]);
      acc[2][0] = fmaf(pA.z, vv.x, acc[2][0]); acc[2][1] = fmaf(pA.z, vv.y, acc[2][1]);
      acc[3][0] = fmaf(pA.w, vv.x, acc[3][0]); acc[3][1] = fmaf(pA.w, vv.y, acc[3][1]);
    }
    __syncthreads();
  }
  // transpose through LDS for coalesced-in-n stores
#pragma unroll
  for (int r = 0; r < 4; ++r) {
    obuf[(2 * cp + 0) * 17 + (qd << 2) + r] = acc[r][0];
    obuf[(2 * cp + 1) * 17 + (qd << 2) + r] = acc[r][1];
  }
  __syncthreads();
  float g = gamma[0];
  for (int idx = t; idx < 2048; idx += 256) {
    int c = idx >> 4, nn = idx & 15;
    size_t o = ((size_t)(b * 128 + c) << 12) + n0 + nn;
    sa1[o] = fmaf(g, obuf[c * 17 + nn], sa0[o]);
  }
}

// ---------------- K6a: CAM Gram energy, block per row c, all threads ---------
__global__ __launch_bounds__(256) void k_cam_energy(const float* __restrict__ f,
                                                    float* __restrict__ energy) {
  __shared__ float fc[4096];
  __shared__ float part[256];
  int t = threadIdx.x;
  int c = blockIdx.x, b = blockIdx.y;
  const float* fr = f + ((size_t)(b * 128 + c) << 12);
  for (int i = t; i < 4096; i += 256) fc[i] = fr[i];
  __syncthreads();
  int d = t & 127, seg = t >> 7;
  const float* fd = f + ((size_t)(b * 128 + d) << 12) + seg * 2048;
  const float* fcs = fc + seg * 2048;
  float acc = 0.f;
  for (int nn = 0; nn < 2048; ++nn) acc = fmaf(fcs[nn], fd[nn], acc);
  part[t] = acc;
  __syncthreads();
  if (t < 128)
    energy[((b * 128 + c) << 7) + t] = part[t] + part[t + 128];
}

// ---------------- K6b: CAM softmax row (attn = softmax(rowmax - e)) ----------
__global__ void k_cam_softmax(const float* __restrict__ energy, float* __restrict__ attn) {
  int lane = threadIdx.x;   // 64
  int c = blockIdx.x, b = blockIdx.y;
  const float* e = energy + ((b * 128 + c) << 7);
  float e0 = e[lane], e1 = e[lane + 64];
  float mn = fminf(e0, e1);
#pragma unroll
  for (int off = 32; off >= 1; off >>= 1) mn = fminf(mn, __shfl_xor(mn, off));
  float p0 = __expf(fminf(mn - e0, 0.f)), p1 = __expf(fminf(mn - e1, 0.f));
  float s = p0 + p1;
#pragma unroll
  for (int off = 32; off >= 1; off >>= 1) s += __shfl_xor(s, off);
  float inv = 1.f / s;
  float* a = attn + ((b * 128 + c) << 7);
  a[lane] = p0 * inv;
  a[lane + 64] = p1 * inv;
}

// ---------------- K7: CAM out + residual -------------------------------------
__global__ __launch_bounds__(256) void k_cam_out(const float* __restrict__ f,
    const float* __restrict__ attn, const float* __restrict__ gamma,
    float* __restrict__ sc1) {
  __shared__ float at2[128 * 16];
  int t = threadIdx.x;
  int b = blockIdx.z, c0 = blockIdx.y * 16;
  int n = blockIdx.x * 256 + t;
  for (int idx = t; idx < 2048; idx += 256) {
    int d = idx >> 4, cc = idx & 15;
    at2[idx] = attn[((b * 128 + c0 + cc) << 7) + d];
  }
  __syncthreads();
  float acc[16] = {};
  const float* fb = f + ((size_t)b * 128 << 12) + n;
  for (int d = 0; d < 128; ++d) {
    float fv = fb[d << 12];
    const float* ap = at2 + d * 16;
#pragma unroll
    for (int cc = 0; cc < 16; ++cc) acc[cc] = fmaf(ap[cc], fv, acc[cc]);
  }
  float g = gamma[0];
#pragma unroll
  for (int cc = 0; cc < 16; ++cc) {
    size_t o = ((size_t)(b * 128 + c0 + cc) << 12) + n;
    sc1[o] = fmaf(g, acc[cc], f[o]);
  }
}

// ---------------- K8: BN+ReLU + 1x1 conv 128->512, 16 co per block -----------
__global__ __launch_bounds__(256) void k_branch_out(
    const float* __restrict__ sa1, const float* __restrict__ sc1,
    const float* __restrict__ wa_, const float* __restrict__ ba_,
    const float* __restrict__ ma_, const float* __restrict__ va_,
    const float* __restrict__ wc_, const float* __restrict__ bc_,
    const float* __restrict__ mc_, const float* __restrict__ vc_,
    const float* __restrict__ Wa, const float* __restrict__ Ba,
    const float* __restrict__ Wc, const float* __restrict__ Bc,
    u16* __restrict__ sa2, u16* __restrict__ sc2) {
  int z = blockIdx.z;
  int b = z & 1, br = z >> 1;
  const float* src = br ? sc1 : sa1;
  const float* bw = br ? wc_ : wa_;
  const float* bb = br ? bc_ : ba_;
  const float* bm = br ? mc_ : ma_;
  const float* bvv = br ? vc_ : va_;
  const float* W = br ? Wc : Wa;
  const float* Bs = br ? Bc : Ba;
  u16* dst = br ? sc2 : sa2;
  __shared__ float wl[128 * 16];
  __shared__ float scl[128], shf[128];
  int t = threadIdx.x;
  int co0 = blockIdx.y * 16;
  int n = blockIdx.x * 256 + t;
  if (t < 128) {
    float s = bw[t] * rsqrtf(bvv[t] + 1e-5f);
    scl[t] = s;
    shf[t] = bb[t] - bm[t] * s;
  }
  for (int idx = t; idx < 2048; idx += 256) {
    int ci = idx >> 4, cc = idx & 15;
    wl[idx] = W[(co0 + cc) * 128 + ci];
  }
  __syncthreads();
  float acc[16] = {};
  const float* sp = src + ((size_t)b * 128 << 12) + n;
  for (int ci = 0; ci < 128; ++ci) {
    float xv = fmaxf(fmaf(sp[ci << 12], scl[ci], shf[ci]), 0.f);
    const float* wp = wl + ci * 16;
    float4 w0 = *(const float4*)wp;
    float4 w1 = *(const float4*)(wp + 4);
    float4 w2 = *(const float4*)(wp + 8);
    float4 w3 = *(const float4*)(wp + 12);
    acc[0] = fmaf(w0.x, xv, acc[0]);  acc[1] = fmaf(w0.y, xv, acc[1]);
    acc[2] = fmaf(w0.z, xv, acc[2]);  acc[3] = fmaf(w0.w, xv, acc[3]);
    acc[4] = fmaf(w1.x, xv, acc[4]);  acc[5] = fmaf(w1.y, xv, acc[5]);
    acc[6] = fmaf(w1.z, xv, acc[6]);  acc[7] = fmaf(w1.w, xv, acc[7]);
    acc[8] = fmaf(w2.x, xv, acc[8]);  acc[9] = fmaf(w2.y, xv, acc[9]);
    acc[10] = fmaf(w2.z, xv, acc[10]); acc[11] = fmaf(w2.w, xv, acc[11]);
    acc[12] = fmaf(w3.x, xv, acc[12]); acc[13] = fmaf(w3.y, xv, acc[13]);
    acc[14] = fmaf(w3.z, xv, acc[14]); acc[15] = fmaf(w3.w, xv, acc[15]);
  }
#pragma unroll
  for (int cc = 0; cc < 16; ++cc) {
    dst[((size_t)(b * 512 + co0 + cc) << 12) + n] = f2bf(acc[cc] + Bs[co0 + cc]);
  }
}

// ---------------- K9: fusion + all three class heads, f32 outputs ------------
__global__ __launch_bounds__(256) void k_heads(const u16* __restrict__ sa2,
    const u16* __restrict__ sc2,
    const float* __restrict__ wf, const float* __restrict__ wa, const float* __restrict__ wc,
    const float* __restrict__ bfb, const float* __restrict__ bab, const float* __restrict__ bcb,
    float* __restrict__ outFusion, float* __restrict__ outCls) {
  int t = threadIdx.x;
  int b = blockIdx.y;
  int n = blockIdx.x * 256 + t;
  float af[5] = {}, aa[5] = {}, ac[5] = {};
  for (int c = 0; c < 512; ++c) {
    size_t o = ((size_t)(b * 512 + c) << 12) + n;
    float a = bf2f(sa2[o]), cc = bf2f(sc2[o]);
    float s = a + cc;
    outFusion[o] = s;
#pragma unroll
    for (int cls = 0; cls < 5; ++cls) {
      af[cls] = fmaf(wf[cls * 512 + c], s, af[cls]);
      aa[cls] = fmaf(wa[cls * 512 + c], a, aa[cls]);
      ac[cls] = fmaf(wc[cls * 512 + c], cc, ac[cls]);
    }
  }
#pragma unroll
  for (int cls = 0; cls < 5; ++cls) {
    int o = ((b * 5 + cls) << 12) + n;
    outCls[o] = af[cls] + bfb[cls];
    outCls[40960 + o] = aa[cls] + bab[cls];
    outCls[81920 + o] = ac[cls] + bcb[cls];
  }
}

extern "C" void kernel_launch(void* const* d_in, const int* in_sizes, int n_in,
                              void* d_out, int out_size, void* d_ws, size_t ws_size,
                              hipStream_t stream) {
  (void)in_sizes; (void)n_in; (void)out_size; (void)ws_size;
  const float* x      = (const float*)d_in[0];
  const float* bnaw   = (const float*)d_in[1];
  const float* bnab   = (const float*)d_in[2];
  const float* bnam   = (const float*)d_in[3];
  const float* bnav   = (const float*)d_in[4];
  const float* convaw = (const float*)d_in[5];
  const float* bncw   = (const float*)d_in[6];
  const float* bncb   = (const float*)d_in[7];
  const float* bncm   = (const float*)d_in[8];
  const float* bncv   = (const float*)d_in[9];
  const float* convcw = (const float*)d_in[10];
  const float* pqw    = (const float*)d_in[11];
  const float* pqb    = (const float*)d_in[12];
  const float* pkw    = (const float*)d_in[13];
  const float* pkb    = (const float*)d_in[14];
  const float* pvw    = (const float*)d_in[15];
  const float* pvb    = (const float*)d_in[16];
  const float* pgam   = (const float*)d_in[17];
  const float* cgam   = (const float*)d_in[18];
  const float* bna1w  = (const float*)d_in[19];
  const float* bna1b  = (const float*)d_in[20];
  const float* bna1m  = (const float*)d_in[21];
  const float* bna1v  = (const float*)d_in[22];
  const float* conva1w = (const float*)d_in[23];
  const float* conva1b = (const float*)d_in[24];
  const float* bnc1w  = (const float*)d_in[25];
  const float* bnc1b  = (const float*)d_in[26];
  const float* bnc1m  = (const float*)d_in[27];
  const float* bnc1v  = (const float*)d_in[28];
  const float* convc1w = (const float*)d_in[29];
  const float* convc1b = (const float*)d_in[30];
  const float* outaw  = (const float*)d_in[31];
  const float* outab  = (const float*)d_in[32];
  const float* outcw  = (const float*)d_in[33];
  const float* outcb  = (const float*)d_in[34];
  const float* outfw  = (const float*)d_in[35];
  const float* outfb  = (const float*)d_in[36];

  char* wsb = (char*)d_ws;
  size_t off = 0;
  auto take = [&](size_t bytes) -> void* {
    void* p = wsb + off;
    off += (bytes + 255) & ~(size_t)255;
    return p;
  };
  float* wvT   = (float*)take((size_t)128 * 128 * 4);
  float* xa    = (float*)take((size_t)2 * 512 * 4096 * 4);
  float* xcb   = (float*)take((size_t)2 * 512 * 4096 * 4);
  float* sa0   = (float*)take((size_t)2 * 128 * 4096 * 4);
  float* sc0   = (float*)take((size_t)2 * 128 * 4096 * 4);
  float* qb    = (float*)take((size_t)2 * 16 * 4096 * 4);
  float* kbuf  = (float*)take((size_t)2 * 16 * 4096 * 4);
  float* vt    = (float*)take((size_t)2 * 4096 * 128 * 4);
  float* rmax  = (float*)take((size_t)2 * 4096 * 4);
  float* rinv  = (float*)take((size_t)2 * 4096 * 4);
  float* sa1   = (float*)take((size_t)2 * 128 * 4096 * 4);
  float* sc1   = (float*)take((size_t)2 * 128 * 4096 * 4);
  float* energy = (float*)take((size_t)2 * 128 * 128 * 4);
  float* attn  = (float*)take((size_t)2 * 128 * 128 * 4);
  u16*   sa2   = (u16*)take((size_t)2 * 512 * 4096 * 2);
  u16*   sc2   = (u16*)take((size_t)2 * 512 * 4096 * 2);

  float* outF = (float*)d_out;
  float* outCls = outF + (size_t)2 * 512 * 4096;

  k_prep_wv<<<64, 256, 0, stream>>>(pvw, wvT);
  k_bnrelu2<<<4096, 256, 0, stream>>>(x, bnaw, bnab, bnam, bnav,
                                      bncw, bncb, bncm, bncv, xa, xcb);
  k_conv3t<<<dim3(16, 32, 4), 256, 0, stream>>>(xa, xcb, convaw, convcw, sa0, sc0);
  k_qk<<<dim3(16, 32, 2), 256, 0, stream>>>(sa0, pqw, pqb, pkw, pkb, qb, kbuf);
  k_vt<<<dim3(2048, 2), 256, 0, stream>>>(sa0, wvT, pvb, vt);
  k_pam_stats<<<dim3(1024, 2), 256, 0, stream>>>(qb, kbuf, rmax, rinv);
  k_pam_pv<<<dim3(256, 2), 256, 0, stream>>>(qb, kbuf, vt, rmax, rinv, sa0, pgam, sa1);
  k_cam_energy<<<dim3(128, 2), 256, 0, stream>>>(sc0, energy);
  k_cam_softmax<<<dim3(128, 2), 64, 0, stream>>>(energy, attn);
  k_cam_out<<<dim3(16, 8, 2), 256, 0, stream>>>(sc0, attn, cgam, sc1);
  k_branch_out<<<dim3(16, 32, 4), 256, 0, stream>>>(sa1, sc1,
      bna1w, bna1b, bna1m, bna1v, bnc1w, bnc1b, bnc1m, bnc1v,
      conva1w, conva1b, convc1w, convc1b, sa2, sc2);
  k_heads<<<dim3(16, 2), 256, 0, stream>>>(sa2, sc2, outfw, outaw, outcw,
                                           outfb, outab, outcb, outF, outCls);
}

// Round 9
// 1276.738 us; speedup vs baseline: 1.2882x; 1.2882x over previous
//
#include <hip/hip_runtime.h>

using u16 = unsigned short;

__device__ __forceinline__ float bf2f(u16 u) {
  return __uint_as_float(((unsigned int)u) << 16);
}
__device__ __forceinline__ u16 f2bf(float f) {
  unsigned int u = __float_as_uint(f);
  unsigned int r = u + 0x7FFFu + ((u >> 16) & 1u);
  return (u16)(r >> 16);
}

// ---------------- K0: transpose pam_v_w [c][ci] -> wvT [ci][c] ---------------
__global__ void k_prep_wv(const float* __restrict__ wv, float* __restrict__ wvT) {
  int idx = blockIdx.x * 256 + threadIdx.x;   // 16384
  int ci = idx >> 7, c = idx & 127;
  wvT[ci * 128 + c] = wv[c * 128 + ci];
}

// ---------------- K1: BN+ReLU for both branches, f32 out ---------------------
__global__ void k_bnrelu2(const float* __restrict__ x,
    const float* __restrict__ wa, const float* __restrict__ ba,
    const float* __restrict__ ma, const float* __restrict__ va,
    const float* __restrict__ wc, const float* __restrict__ bc,
    const float* __restrict__ mc, const float* __restrict__ vc,
    float* __restrict__ xa, float* __restrict__ xcb) {
  int i4 = (blockIdx.x * 256 + threadIdx.x) * 4;   // over 2*512*4096
  int c = (i4 >> 12) & 511;
  float sA = wa[c] * rsqrtf(va[c] + 1e-5f);
  float bA = ba[c] - ma[c] * sA;
  float sC = wc[c] * rsqrtf(vc[c] + 1e-5f);
  float bC = bc[c] - mc[c] * sC;
  float4 xv = *(const float4*)(x + i4);
  float4 oa, oc;
  oa.x = fmaxf(xv.x * sA + bA, 0.f); oc.x = fmaxf(xv.x * sC + bC, 0.f);
  oa.y = fmaxf(xv.y * sA + bA, 0.f); oc.y = fmaxf(xv.y * sC + bC, 0.f);
  oa.z = fmaxf(xv.z * sA + bA, 0.f); oc.z = fmaxf(xv.z * sC + bC, 0.f);
  oa.w = fmaxf(xv.w * sA + bA, 0.f); oc.w = fmaxf(xv.w * sC + bC, 0.f);
  *(float4*)(xa + i4) = oa;
  *(float4*)(xcb + i4) = oc;
}

// ---------------- K2: 3x3 conv, co-tile 8, split-K over ci (2 halves) --------
// block: 256 thr = 4 rows x 64 cols; computes 8 co, 256 ci; atomicAdd combine.
// grid: (32 = hg(16) x ks(2), 16 co-groups, 4: z = b + 2*branch) -> 2048 blocks
__global__ __launch_bounds__(256) void k_conv3t(
    const float* __restrict__ xa, const float* __restrict__ xcb,
    const float* __restrict__ wa, const float* __restrict__ wc,
    float* __restrict__ sa0, float* __restrict__ sc0) {
  __shared__ float ls[16 * 396];   // 16 ci x 6 rows x 66 (w-halo), zero-padded
  int t = threadIdx.x;
  int xg = blockIdx.x;
  int hg = xg & 15, ks = xg >> 4;
  int cg = blockIdx.y, z = blockIdx.z;
  int b = z & 1, br = z >> 1;
  const float* xin = br ? xcb : xa;
  const float* wconv = br ? wc : wa;
  float* out = br ? sc0 : sa0;
  int h0 = hg * 4;
  int w = t & 63, hl = t >> 6;
  int co0 = cg * 8;
  float acc[8] = {};
  const float* xb = xin + ((size_t)b * 512 << 12);
  int ciBeg = ks * 256;
  for (int ci0 = ciBeg; ci0 < ciBeg + 256; ci0 += 16) {
    __syncthreads();
    for (int idx = t; idx < 6336; idx += 256) {
      int ci_l = idx / 396;
      int rem = idx - ci_l * 396;
      int row = rem / 66;
      int w66 = rem - row * 66;
      int gh = h0 - 1 + row;
      int gw = w66 - 1;
      float v = 0.f;
      if (gh >= 0 && gh < 64 && gw >= 0 && gw < 64)
        v = xb[((size_t)(ci0 + ci_l) << 12) + (gh << 6) + gw];
      ls[idx] = v;
    }
    __syncthreads();
    for (int ci_l = 0; ci_l < 16; ++ci_l) {
      const float* c = ls + ci_l * 396 + (hl + 1) * 66 + (w + 1);
      float x00 = c[-67], x01 = c[-66], x02 = c[-65];
      float x10 = c[-1],  x11 = c[0],   x12 = c[1];
      float x20 = c[65],  x21 = c[66],  x22 = c[67];
      const float* wp = wconv + (size_t)co0 * 4608 + (ci0 + ci_l) * 9;
#pragma unroll
      for (int co = 0; co < 8; ++co) {
        const float* wq = wp + co * 4608;   // block-uniform -> scalar loads
        acc[co] = fmaf(wq[0], x00, fmaf(wq[1], x01, fmaf(wq[2], x02,
                  fmaf(wq[3], x10, fmaf(wq[4], x11, fmaf(wq[5], x12,
                  fmaf(wq[6], x20, fmaf(wq[7], x21, fmaf(wq[8], x22, acc[co])))))))));
      }
    }
  }
  int hw = ((h0 + hl) << 6) + w;
#pragma unroll
  for (int co = 0; co < 8; ++co)
    atomicAdd(&out[((size_t)(b * 128 + co0 + co) << 12) + hw], acc[co]);
}

// ---------------- K3a: 1x1 conv -> q,k ([b][16][4096] f32) -------------------
__global__ void k_qk(const float* __restrict__ sa0,
    const float* __restrict__ wq, const float* __restrict__ bq,
    const float* __restrict__ wk, const float* __restrict__ bk,
    float* __restrict__ qb, float* __restrict__ kb) {
  int n = blockIdx.x * 256 + threadIdx.x;
  int co = blockIdx.y, b = blockIdx.z;
  const float* w; float* dst; float bias;
  if (co < 16) { w = wq + co * 128; bias = bq[co]; dst = qb + ((b * 16 + co) << 12); }
  else { int c2 = co - 16; w = wk + c2 * 128; bias = bk[c2]; dst = kb + ((b * 16 + c2) << 12); }
  const float* s = sa0 + ((size_t)b * 128 << 12) + n;
  float acc = bias;
  for (int ci = 0; ci < 128; ++ci) acc = fmaf(w[ci], s[ci << 12], acc);
  dst[n] = acc;
}

// ---------------- K3b: 1x1 conv -> v, stored transposed vt[b][n][c] ----------
__global__ void k_vt(const float* __restrict__ sa0, const float* __restrict__ wvT,
                     const float* __restrict__ bv, float* __restrict__ vt) {
  int t = threadIdx.x;
  int c = t & 127, nh = t >> 7;
  int n = blockIdx.x * 2 + nh, b = blockIdx.y;
  const float* s = sa0 + ((size_t)b * 128 << 12) + n;
  float acc = bv[c];
  for (int ci = 0; ci < 128; ++ci) acc = fmaf(wvT[ci * 128 + c], s[ci << 12], acc);
  vt[((size_t)(b * 4096 + n)) * 128 + c] = acc;
}

// ---------------- K4: PAM softmax row stats (max, 1/sum) ---------------------
__global__ __launch_bounds__(256) void k_pam_stats(const float* __restrict__ qb,
    const float* __restrict__ kb, float* __restrict__ rmax, float* __restrict__ rinv) {
  int t = threadIdx.x, lane = t & 63, wid = t >> 6;
  int b = blockIdx.y;
  int n = blockIdx.x * 4 + wid;
  float qreg[16];
  const float* qp = qb + ((size_t)b * 16 << 12) + n;
#pragma unroll
  for (int ch = 0; ch < 16; ++ch) qreg[ch] = qp[ch << 12];
  const float* kp = kb + ((size_t)b * 16 << 12);
  float mx = -1e30f, se = 0.f;
  for (int m = lane; m < 4096; m += 64) {
    float e = 0.f;
#pragma unroll
    for (int ch = 0; ch < 16; ++ch) e = fmaf(qreg[ch], kp[(ch << 12) + m], e);
    float nm = fmaxf(mx, e);
    se = se * __expf(mx - nm) + __expf(e - nm);
    mx = nm;
  }
#pragma unroll
  for (int off = 32; off >= 1; off >>= 1) {
    float om = __shfl_xor(mx, off);
    float os = __shfl_xor(se, off);
    float nm = fmaxf(mx, om);
    se = se * __expf(mx - nm) + os * __expf(om - nm);
    mx = nm;
  }
  if (lane == 0) { rmax[(b << 12) + n] = mx; rinv[(b << 12) + n] = 1.f / se; }
}

// ---------------- K5: PAM PV, 16-n tile per block, 512 blocks ----------------
__global__ __launch_bounds__(256) void k_pam_pv(const float* __restrict__ qb,
    const float* __restrict__ kb, const float* __restrict__ vt,
    const float* __restrict__ rmax, const float* __restrict__ rinv,
    const float* __restrict__ sa0, const float* __restrict__ gamma,
    float* __restrict__ sa1) {
  __shared__ float qs[256];        // [ch][16 n]
  __shared__ float ks[1024];       // [ch][64 m]
  __shared__ float pbs[1024];      // [64 m][16 n]
  __shared__ float mxs[16], invs[16];
  __shared__ float obuf[128 * 17];
  int t = threadIdx.x;
  int b = blockIdx.y, n0 = blockIdx.x * 16;
  {
    int ch = t >> 4, r = t & 15;
    qs[t] = qb[((b * 16 + ch) << 12) + n0 + r];
  }
  if (t < 16) { mxs[t] = rmax[(b << 12) + n0 + t]; invs[t] = rinv[(b << 12) + n0 + t]; }
  int cp = t & 63, qd = t >> 6;
  float acc[4][2] = {};
  const float* kpb = kb + ((size_t)b * 16 << 12);
  for (int m0 = 0; m0 < 4096; m0 += 64) {
    for (int idx = t; idx < 1024; idx += 256) {
      int ch = idx >> 6, mm = idx & 63;
      ks[idx] = kpb[(ch << 12) + m0 + mm];
    }
    __syncthreads();
    {
      int m = t >> 2, r0 = (t & 3) * 4;
      float e0 = 0.f, e1 = 0.f, e2 = 0.f, e3 = 0.f;
#pragma unroll
      for (int ch = 0; ch < 16; ++ch) {
        float kk = ks[(ch << 6) + m];
        float4 qv = *(const float4*)(qs + (ch << 4) + r0);
        e0 = fmaf(kk, qv.x, e0); e1 = fmaf(kk, qv.y, e1);
        e2 = fmaf(kk, qv.z, e2); e3 = fmaf(kk, qv.w, e3);
      }
      float4 mv = *(const float4*)(mxs + r0);
      float4 iv = *(const float4*)(invs + r0);
      float4 pv;
      pv.x = __expf(fminf(e0 - mv.x, 0.f)) * iv.x;
      pv.y = __expf(fminf(e1 - mv.y, 0.f)) * iv.y;
      pv.z = __expf(fminf(e2 - mv.z, 0.f)) * iv.z;
      pv.w = __expf(fminf(e3 - mv.w, 0.f)) * iv.w;
      *(float4*)(pbs + (m << 4) + r0) = pv;
    }
    __syncthreads();
    const float* vp = vt + ((size_t)(b * 4096 + m0)) * 128 + (cp << 1);
#pragma unroll 4
    for (int mm = 0; mm < 64; ++mm) {
      float2 vv = *(const float2*)(vp + mm * 128);
      const float* pp = pbs + (mm << 4) + (qd << 2);
      float4 pA = *(const float4*)pp;
      acc[0][0] = fmaf(pA.x, vv.x, acc[0][0]); acc[0][1] = fmaf(pA.x, vv.y, acc[0][1]);
      acc[1][0] = fmaf(pA.y, vv.x, acc[1][0]); acc[1][1] = fmaf(pA.y, vv.y, acc[1][1]);
      acc[2][0] = fmaf(pA.z, vv.x, acc[2][0]); acc[2][1] = fmaf(pA.z, vv.y, acc[2][1]);
      acc[3][0] = fmaf(pA.w, vv.x, acc[3][0]); acc[3][1] = fmaf(pA.w, vv.y, acc[3][1]);
    }
    __syncthreads();
  }
#pragma unroll
  for (int r = 0; r < 4; ++r) {
    obuf[(2 * cp + 0) * 17 + (qd << 2) + r] = acc[r][0];
    obuf[(2 * cp + 1) * 17 + (qd << 2) + r] = acc[r][1];
  }
  __syncthreads();
  float g = gamma[0];
  for (int idx = t; idx < 2048; idx += 256) {
    int c = idx >> 4, nn = idx & 15;
    size_t o = ((size_t)(b * 128 + c) << 12) + n0 + nn;
    sa1[o] = fmaf(g, obuf[c * 17 + nn], sa0[o]);
  }
}

// ---------------- K6a: CAM Gram energy, block per row c, all threads ---------
__global__ __launch_bounds__(256) void k_cam_energy(const float* __restrict__ f,
                                                    float* __restrict__ energy) {
  __shared__ float fc[4096];
  __shared__ float part[256];
  int t = threadIdx.x;
  int c = blockIdx.x, b = blockIdx.y;
  const float* fr = f + ((size_t)(b * 128 + c) << 12);
  for (int i = t; i < 4096; i += 256) fc[i] = fr[i];
  __syncthreads();
  int d = t & 127, seg = t >> 7;
  const float* fd = f + ((size_t)(b * 128 + d) << 12) + seg * 2048;
  const float* fcs = fc + seg * 2048;
  float acc = 0.f;
  for (int nn = 0; nn < 2048; ++nn) acc = fmaf(fcs[nn], fd[nn], acc);
  part[t] = acc;
  __syncthreads();
  if (t < 128)
    energy[((b * 128 + c) << 7) + t] = part[t] + part[t + 128];
}

// ---------------- K6b: CAM softmax row (attn = softmax(rowmax - e)) ----------
__global__ void k_cam_softmax(const float* __restrict__ energy, float* __restrict__ attn) {
  int lane = threadIdx.x;   // 64
  int c = blockIdx.x, b = blockIdx.y;
  const float* e = energy + ((b * 128 + c) << 7);
  float e0 = e[lane], e1 = e[lane + 64];
  float mn = fminf(e0, e1);
#pragma unroll
  for (int off = 32; off >= 1; off >>= 1) mn = fminf(mn, __shfl_xor(mn, off));
  float p0 = __expf(fminf(mn - e0, 0.f)), p1 = __expf(fminf(mn - e1, 0.f));
  float s = p0 + p1;
#pragma unroll
  for (int off = 32; off >= 1; off >>= 1) s += __shfl_xor(s, off);
  float inv = 1.f / s;
  float* a = attn + ((b * 128 + c) << 7);
  a[lane] = p0 * inv;
  a[lane + 64] = p1 * inv;
}

// ---------------- K7: CAM out + residual -------------------------------------
__global__ __launch_bounds__(256) void k_cam_out(const float* __restrict__ f,
    const float* __restrict__ attn, const float* __restrict__ gamma,
    float* __restrict__ sc1) {
  __shared__ float at2[128 * 16];
  int t = threadIdx.x;
  int b = blockIdx.z, c0 = blockIdx.y * 16;
  int n = blockIdx.x * 256 + t;
  for (int idx = t; idx < 2048; idx += 256) {
    int d = idx >> 4, cc = idx & 15;
    at2[idx] = attn[((b * 128 + c0 + cc) << 7) + d];
  }
  __syncthreads();
  float acc[16] = {};
  const float* fb = f + ((size_t)b * 128 << 12) + n;
  for (int d = 0; d < 128; ++d) {
    float fv = fb[d << 12];
    const float* ap = at2 + d * 16;
#pragma unroll
    for (int cc = 0; cc < 16; ++cc) acc[cc] = fmaf(ap[cc], fv, acc[cc]);
  }
  float g = gamma[0];
#pragma unroll
  for (int cc = 0; cc < 16; ++cc) {
    size_t o = ((size_t)(b * 128 + c0 + cc) << 12) + n;
    sc1[o] = fmaf(g, acc[cc], f[o]);
  }
}

// ---------------- K8: BN+ReLU + 1x1 conv 128->512, 16 co per block -----------
__global__ __launch_bounds__(256) void k_branch_out(
    const float* __restrict__ sa1, const float* __restrict__ sc1,
    const float* __restrict__ wa_, const float* __restrict__ ba_,
    const float* __restrict__ ma_, const float* __restrict__ va_,
    const float* __restrict__ wc_, const float* __restrict__ bc_,
    const float* __restrict__ mc_, const float* __restrict__ vc_,
    const float* __restrict__ Wa, const float* __restrict__ Ba,
    const float* __restrict__ Wc, const float* __restrict__ Bc,
    u16* __restrict__ sa2, u16* __restrict__ sc2) {
  int z = blockIdx.z;
  int b = z & 1, br = z >> 1;
  const float* src = br ? sc1 : sa1;
  const float* bw = br ? wc_ : wa_;
  const float* bb = br ? bc_ : ba_;
  const float* bm = br ? mc_ : ma_;
  const float* bvv = br ? vc_ : va_;
  const float* W = br ? Wc : Wa;
  const float* Bs = br ? Bc : Ba;
  u16* dst = br ? sc2 : sa2;
  __shared__ float wl[128 * 16];
  __shared__ float scl[128], shf[128];
  int t = threadIdx.x;
  int co0 = blockIdx.y * 16;
  int n = blockIdx.x * 256 + t;
  if (t < 128) {
    float s = bw[t] * rsqrtf(bvv[t] + 1e-5f);
    scl[t] = s;
    shf[t] = bb[t] - bm[t] * s;
  }
  for (int idx = t; idx < 2048; idx += 256) {
    int ci = idx >> 4, cc = idx & 15;
    wl[idx] = W[(co0 + cc) * 128 + ci];
  }
  __syncthreads();
  float acc[16] = {};
  const float* sp = src + ((size_t)b * 128 << 12) + n;
  for (int ci = 0; ci < 128; ++ci) {
    float xv = fmaxf(fmaf(sp[ci << 12], scl[ci], shf[ci]), 0.f);
    const float* wp = wl + ci * 16;
    float4 w0 = *(const float4*)wp;
    float4 w1 = *(const float4*)(wp + 4);
    float4 w2 = *(const float4*)(wp + 8);
    float4 w3 = *(const float4*)(wp + 12);
    acc[0] = fmaf(w0.x, xv, acc[0]);  acc[1] = fmaf(w0.y, xv, acc[1]);
    acc[2] = fmaf(w0.z, xv, acc[2]);  acc[3] = fmaf(w0.w, xv, acc[3]);
    acc[4] = fmaf(w1.x, xv, acc[4]);  acc[5] = fmaf(w1.y, xv, acc[5]);
    acc[6] = fmaf(w1.z, xv, acc[6]);  acc[7] = fmaf(w1.w, xv, acc[7]);
    acc[8] = fmaf(w2.x, xv, acc[8]);  acc[9] = fmaf(w2.y, xv, acc[9]);
    acc[10] = fmaf(w2.z, xv, acc[10]); acc[11] = fmaf(w2.w, xv, acc[11]);
    acc[12] = fmaf(w3.x, xv, acc[12]); acc[13] = fmaf(w3.y, xv, acc[13]);
    acc[14] = fmaf(w3.z, xv, acc[14]); acc[15] = fmaf(w3.w, xv, acc[15]);
  }
#pragma unroll
  for (int cc = 0; cc < 16; ++cc) {
    dst[((size_t)(b * 512 + co0 + cc) << 12) + n] = f2bf(acc[cc] + Bs[co0 + cc]);
  }
}

// ---------------- K9a: fusion + partial class-head sums (8-way c split) ------
__global__ __launch_bounds__(256) void k_heads(const u16* __restrict__ sa2,
    const u16* __restrict__ sc2,
    const float* __restrict__ wf, const float* __restrict__ wa, const float* __restrict__ wc,
    float* __restrict__ outFusion, float* __restrict__ clsacc) {
  __shared__ float lw[3 * 5 * 64];
  int t = threadIdx.x;
  int b = blockIdx.y, co0 = blockIdx.z * 64;
  int n = blockIdx.x * 256 + t;
  for (int idx = t; idx < 960; idx += 256) {
    int arr = idx / 320, rest = idx - arr * 320;
    int cls = rest >> 6, cc = rest & 63;
    const float* w = arr == 0 ? wf : (arr == 1 ? wa : wc);
    lw[idx] = w[cls * 512 + co0 + cc];
  }
  __syncthreads();
  float af[5] = {}, aa[5] = {}, ac[5] = {};
  for (int cc = 0; cc < 64; ++cc) {
    size_t o = ((size_t)(b * 512 + co0 + cc) << 12) + n;
    float a = bf2f(sa2[o]), c = bf2f(sc2[o]);
    float s = a + c;
    outFusion[o] = s;
#pragma unroll
    for (int cls = 0; cls < 5; ++cls) {
      af[cls] = fmaf(lw[0 * 320 + cls * 64 + cc], s, af[cls]);
      aa[cls] = fmaf(lw[1 * 320 + cls * 64 + cc], a, aa[cls]);
      ac[cls] = fmaf(lw[2 * 320 + cls * 64 + cc], c, ac[cls]);
    }
  }
#pragma unroll
  for (int cls = 0; cls < 5; ++cls) {
    int o = ((b * 5 + cls) << 12) + n;
    atomicAdd(&clsacc[o], af[cls]);
    atomicAdd(&clsacc[40960 + o], aa[cls]);
    atomicAdd(&clsacc[81920 + o], ac[cls]);
  }
}

// ---------------- K9b: add bias, f32 out -------------------------------------
__global__ void k_heads_final(const float* __restrict__ clsacc,
    const float* __restrict__ bf_, const float* __restrict__ ba_,
    const float* __restrict__ bc_, float* __restrict__ outCls) {
  int idx = blockIdx.x * 256 + threadIdx.x;   // 122880
  int arr = idx / 40960;
  int rest = idx - arr * 40960;
  int cls = (rest >> 12) % 5;
  const float* bp = arr == 0 ? bf_ : (arr == 1 ? ba_ : bc_);
  outCls[idx] = clsacc[idx] + bp[cls];
}

extern "C" void kernel_launch(void* const* d_in, const int* in_sizes, int n_in,
                              void* d_out, int out_size, void* d_ws, size_t ws_size,
                              hipStream_t stream) {
  (void)in_sizes; (void)n_in; (void)out_size; (void)ws_size;
  const float* x      = (const float*)d_in[0];
  const float* bnaw   = (const float*)d_in[1];
  const float* bnab   = (const float*)d_in[2];
  const float* bnam   = (const float*)d_in[3];
  const float* bnav   = (const float*)d_in[4];
  const float* convaw = (const float*)d_in[5];
  const float* bncw   = (const float*)d_in[6];
  const float* bncb   = (const float*)d_in[7];
  const float* bncm   = (const float*)d_in[8];
  const float* bncv   = (const float*)d_in[9];
  const float* convcw = (const float*)d_in[10];
  const float* pqw    = (const float*)d_in[11];
  const float* pqb    = (const float*)d_in[12];
  const float* pkw    = (const float*)d_in[13];
  const float* pkb    = (const float*)d_in[14];
  const float* pvw    = (const float*)d_in[15];
  const float* pvb    = (const float*)d_in[16];
  const float* pgam   = (const float*)d_in[17];
  const float* cgam   = (const float*)d_in[18];
  const float* bna1w  = (const float*)d_in[19];
  const float* bna1b  = (const float*)d_in[20];
  const float* bna1m  = (const float*)d_in[21];
  const float* bna1v  = (const float*)d_in[22];
  const float* conva1w = (const float*)d_in[23];
  const float* conva1b = (const float*)d_in[24];
  const float* bnc1w  = (const float*)d_in[25];
  const float* bnc1b  = (const float*)d_in[26];
  const float* bnc1m  = (const float*)d_in[27];
  const float* bnc1v  = (const float*)d_in[28];
  const float* convc1w = (const float*)d_in[29];
  const float* convc1b = (const float*)d_in[30];
  const float* outaw  = (const float*)d_in[31];
  const float* outab  = (const float*)d_in[32];
  const float* outcw  = (const float*)d_in[33];
  const float* outcb  = (const float*)d_in[34];
  const float* outfw  = (const float*)d_in[35];
  const float* outfb  = (const float*)d_in[36];

  char* wsb = (char*)d_ws;
  size_t off = 0;
  auto take = [&](size_t bytes) -> void* {
    void* p = wsb + off;
    off += (bytes + 255) & ~(size_t)255;
    return p;
  };
  float* wvT   = (float*)take((size_t)128 * 128 * 4);
  float* xa    = (float*)take((size_t)2 * 512 * 4096 * 4);
  float* xcb   = (float*)take((size_t)2 * 512 * 4096 * 4);
  float* sa0   = (float*)take((size_t)2 * 128 * 4096 * 4);
  float* sc0   = (float*)take((size_t)2 * 128 * 4096 * 4);
  float* qb    = (float*)take((size_t)2 * 16 * 4096 * 4);
  float* kbuf  = (float*)take((size_t)2 * 16 * 4096 * 4);
  float* vt    = (float*)take((size_t)2 * 4096 * 128 * 4);
  float* rmax  = (float*)take((size_t)2 * 4096 * 4);
  float* rinv  = (float*)take((size_t)2 * 4096 * 4);
  float* sa1   = (float*)take((size_t)2 * 128 * 4096 * 4);
  float* sc1   = (float*)take((size_t)2 * 128 * 4096 * 4);
  float* energy = (float*)take((size_t)2 * 128 * 128 * 4);
  float* attn  = (float*)take((size_t)2 * 128 * 128 * 4);
  u16*   sa2   = (u16*)take((size_t)2 * 512 * 4096 * 2);
  u16*   sc2   = (u16*)take((size_t)2 * 512 * 4096 * 2);
  float* clsacc = (float*)take((size_t)3 * 2 * 5 * 4096 * 4);

  float* outF = (float*)d_out;
  float* outCls = outF + (size_t)2 * 512 * 4096;

  hipMemsetAsync(sa0, 0, (size_t)2 * 128 * 4096 * 4, stream);
  hipMemsetAsync(sc0, 0, (size_t)2 * 128 * 4096 * 4, stream);
  hipMemsetAsync(clsacc, 0, (size_t)3 * 2 * 5 * 4096 * 4, stream);

  k_prep_wv<<<64, 256, 0, stream>>>(pvw, wvT);
  k_bnrelu2<<<4096, 256, 0, stream>>>(x, bnaw, bnab, bnam, bnav,
                                      bncw, bncb, bncm, bncv, xa, xcb);
  k_conv3t<<<dim3(32, 16, 4), 256, 0, stream>>>(xa, xcb, convaw, convcw, sa0, sc0);
  k_qk<<<dim3(16, 32, 2), 256, 0, stream>>>(sa0, pqw, pqb, pkw, pkb, qb, kbuf);
  k_vt<<<dim3(2048, 2), 256, 0, stream>>>(sa0, wvT, pvb, vt);
  k_pam_stats<<<dim3(1024, 2), 256, 0, stream>>>(qb, kbuf, rmax, rinv);
  k_pam_pv<<<dim3(256, 2), 256, 0, stream>>>(qb, kbuf, vt, rmax, rinv, sa0, pgam, sa1);
  k_cam_energy<<<dim3(128, 2), 256, 0, stream>>>(sc0, energy);
  k_cam_softmax<<<dim3(128, 2), 64, 0, stream>>>(energy, attn);
  k_cam_out<<<dim3(16, 8, 2), 256, 0, stream>>>(sc0, attn, cgam, sc1);
  k_branch_out<<<dim3(16, 32, 4), 256, 0, stream>>>(sa1, sc1,
      bna1w, bna1b, bna1m, bna1v, bnc1w, bnc1b, bnc1m, bnc1v,
      conva1w, conva1b, convc1w, convc1b, sa2, sc2);
  k_heads<<<dim3(16, 2, 8), 256, 0, stream>>>(sa2, sc2, outfw, outaw, outcw, outF, clsacc);
  k_heads_final<<<480, 256, 0, stream>>>(clsacc, outfb, outab, outcb, outCls);
}

// Round 10
// 916.099 us; speedup vs baseline: 1.7953x; 1.3937x over previous
//
#include <hip/hip_runtime.h>

using u16 = unsigned short;
using short8 = __attribute__((ext_vector_type(8))) short;
using f32x4 = __attribute__((ext_vector_type(4))) float;

struct alignas(8) U16x4 { u16 x, y, z, w; };

__device__ __forceinline__ float bf2f(u16 u) {
  return __uint_as_float(((unsigned int)u) << 16);
}
__device__ __forceinline__ u16 f2bf(float f) {
  unsigned int u = __float_as_uint(f);
  unsigned int r = u + 0x7FFFu + ((u >> 16) & 1u);
  return (u16)(r >> 16);
}

// ---------------- K0a: transpose pam_v_w [c][ci] -> wvT [ci][c] --------------
__global__ void k_prep_wv(const float* __restrict__ wv, float* __restrict__ wvT) {
  int idx = blockIdx.x * 256 + threadIdx.x;   // 16384
  int ci = idx >> 7, c = idx & 127;
  wvT[ci * 128 + c] = wv[c * 128 + ci];
}

// ---------------- K0b: conv weights -> bf16, tap-major Wb[br][co][tap][ci] ---
__global__ void k_prep_w(const float* __restrict__ wa, const float* __restrict__ wc,
                         u16* __restrict__ Wb) {
  int idx = blockIdx.x * 256 + threadIdx.x;   // 2*128*9*512 = 1179648
  int ci = idx & 511;
  int rest = idx >> 9;          // br*128*9 + co*9 + tap
  int tap = rest % 9;
  int rest2 = rest / 9;         // br*128 + co
  int co = rest2 & 127, br = rest2 >> 7;
  const float* w = br ? wc : wa;
  Wb[idx] = f2bf(w[co * 4608 + ci * 9 + tap]);
}

// ---------------- K1: BN+ReLU for both branches, bf16 out --------------------
__global__ void k_bnrelu2(const float* __restrict__ x,
    const float* __restrict__ wa, const float* __restrict__ ba,
    const float* __restrict__ ma, const float* __restrict__ va,
    const float* __restrict__ wc, const float* __restrict__ bc,
    const float* __restrict__ mc, const float* __restrict__ vc,
    u16* __restrict__ xa16, u16* __restrict__ xcb16) {
  int i4 = (blockIdx.x * 256 + threadIdx.x) * 4;   // over 2*512*4096
  int c = (i4 >> 12) & 511;
  float sA = wa[c] * rsqrtf(va[c] + 1e-5f);
  float bA = ba[c] - ma[c] * sA;
  float sC = wc[c] * rsqrtf(vc[c] + 1e-5f);
  float bC = bc[c] - mc[c] * sC;
  float4 xv = *(const float4*)(x + i4);
  U16x4 oa, oc;
  oa.x = f2bf(fmaxf(xv.x * sA + bA, 0.f)); oc.x = f2bf(fmaxf(xv.x * sC + bC, 0.f));
  oa.y = f2bf(fmaxf(xv.y * sA + bA, 0.f)); oc.y = f2bf(fmaxf(xv.y * sC + bC, 0.f));
  oa.z = f2bf(fmaxf(xv.z * sA + bA, 0.f)); oc.z = f2bf(fmaxf(xv.z * sC + bC, 0.f));
  oa.w = f2bf(fmaxf(xv.w * sA + bA, 0.f)); oc.w = f2bf(fmaxf(xv.w * sC + bC, 0.f));
  *(U16x4*)(xa16 + i4) = oa;
  *(U16x4*)(xcb16 + i4) = oc;
}

// ---------------- K2: 3x3 conv via MFMA implicit GEMM ------------------------
// block: 256 thr = 4 waves; tile 32co x 64w (one h row); K = 9 taps x 512 ci.
// grid: (64 h, 4 co-groups, 4: z = b + 2*branch)
__global__ __launch_bounds__(256) void k_conv3m(
    const u16* __restrict__ xa16, const u16* __restrict__ xcb16,
    const u16* __restrict__ Wb,
    float* __restrict__ sa0, float* __restrict__ sc0) {
  __shared__ u16 xl[64 * 40];   // [w][ci_l], stride 40 u16 (16B-aligned rows, 2-way banks)
  int t = threadIdx.x;
  int h = blockIdx.x;
  int co0 = blockIdx.y * 32;
  int z = blockIdx.z;
  int b = z & 1, br = z >> 1;
  const u16* xb = (br ? xcb16 : xa16) + ((size_t)b * 512 << 12);
  const short* wbase = (const short*)(Wb + (size_t)br * 128 * 9 * 512);
  float* out = br ? sc0 : sa0;

  int lane = t & 63, wave = t >> 6;
  int coh = (wave >> 1) << 4;     // 0 or 16
  int nh  = (wave & 1) << 5;      // 0 or 32
  int mi = lane & 15, quad = lane >> 4;

  int ws_ = t & 63;               // staging w (0..63)
  int cig = (t >> 6) << 3;        // staging ci_l base: 0,8,16,24

  f32x4 acc0 = {0.f, 0.f, 0.f, 0.f};
  f32x4 acc1 = {0.f, 0.f, 0.f, 0.f};

  const short* wrow = wbase + ((size_t)(co0 + coh + mi) * 9) * 512;

  for (int tap = 0; tap < 9; ++tap) {
    int dh = tap / 3 - 1, dw = tap % 3 - 1;
    int hh = h + dh;
    if (hh < 0 || hh > 63) continue;          // block-uniform skip
    int wp = ws_ + dw;
    bool valid = (wp >= 0) && (wp < 64);
    const u16* srow = xb + (hh << 6) + wp;
    const short* wtap = wrow + (size_t)tap * 512;
    for (int ci0 = 0; ci0 < 512; ci0 += 32) {
      // gather 8 ci (strided 4096) for fixed w
      short8 v;
      const u16* sp = srow + ((size_t)(ci0 + cig) << 12);
#pragma unroll
      for (int j = 0; j < 8; ++j)
        v[j] = valid ? (short)sp[(size_t)j << 12] : (short)0;
      __syncthreads();                         // prev compute done
      *(short8*)(xl + ws_ * 40 + cig) = v;     // ds_write_b128
      __syncthreads();
      short8 a = *(const short8*)(wtap + ci0 + quad * 8);          // 16B global
      short8 b0 = *(const short8*)(xl + (nh + mi) * 40 + quad * 8);       // ds_read_b128
      short8 b1 = *(const short8*)(xl + (nh + 16 + mi) * 40 + quad * 8);
      acc0 = __builtin_amdgcn_mfma_f32_16x16x32_bf16(a, b0, acc0, 0, 0, 0);
      acc1 = __builtin_amdgcn_mfma_f32_16x16x32_bf16(a, b1, acc1, 0, 0, 0);
    }
  }
  // D layout: col(n)=lane&15, row(m)=quad*4+reg
#pragma unroll
  for (int r = 0; r < 4; ++r) {
    int co = co0 + coh + quad * 4 + r;
    size_t o = ((size_t)(b * 128 + co) << 12) + (h << 6) + nh + mi;
    out[o] = acc0[r];
    out[o + 16] = acc1[r];
  }
}

// ---------------- K3a: 1x1 conv -> q,k ([b][16][4096] f32) -------------------
__global__ void k_qk(const float* __restrict__ sa0,
    const float* __restrict__ wq, const float* __restrict__ bq,
    const float* __restrict__ wk, const float* __restrict__ bk,
    float* __restrict__ qb, float* __restrict__ kb) {
  int n = blockIdx.x * 256 + threadIdx.x;
  int co = blockIdx.y, b = blockIdx.z;
  const float* w; float* dst; float bias;
  if (co < 16) { w = wq + co * 128; bias = bq[co]; dst = qb + ((b * 16 + co) << 12); }
  else { int c2 = co - 16; w = wk + c2 * 128; bias = bk[c2]; dst = kb + ((b * 16 + c2) << 12); }
  const float* s = sa0 + ((size_t)b * 128 << 12) + n;
  float acc = bias;
  for (int ci = 0; ci < 128; ++ci) acc = fmaf(w[ci], s[ci << 12], acc);
  dst[n] = acc;
}

// ---------------- K3b: 1x1 conv -> v, stored transposed vt[b][n][c] ----------
__global__ void k_vt(const float* __restrict__ sa0, const float* __restrict__ wvT,
                     const float* __restrict__ bv, float* __restrict__ vt) {
  int t = threadIdx.x;
  int c = t & 127, nh = t >> 7;
  int n = blockIdx.x * 2 + nh, b = blockIdx.y;
  const float* s = sa0 + ((size_t)b * 128 << 12) + n;
  float acc = bv[c];
  for (int ci = 0; ci < 128; ++ci) acc = fmaf(wvT[ci * 128 + c], s[ci << 12], acc);
  vt[((size_t)(b * 4096 + n)) * 128 + c] = acc;
}

// ---------------- K4: PAM softmax row stats (max, 1/sum) ---------------------
__global__ __launch_bounds__(256) void k_pam_stats(const float* __restrict__ qb,
    const float* __restrict__ kb, float* __restrict__ rmax, float* __restrict__ rinv) {
  int t = threadIdx.x, lane = t & 63, wid = t >> 6;
  int b = blockIdx.y;
  int n = blockIdx.x * 4 + wid;
  float qreg[16];
  const float* qp = qb + ((size_t)b * 16 << 12) + n;
#pragma unroll
  for (int ch = 0; ch < 16; ++ch) qreg[ch] = qp[ch << 12];
  const float* kp = kb + ((size_t)b * 16 << 12);
  float mx = -1e30f, se = 0.f;
  for (int m = lane; m < 4096; m += 64) {
    float e = 0.f;
#pragma unroll
    for (int ch = 0; ch < 16; ++ch) e = fmaf(qreg[ch], kp[(ch << 12) + m], e);
    float nm = fmaxf(mx, e);
    se = se * __expf(mx - nm) + __expf(e - nm);
    mx = nm;
  }
#pragma unroll
  for (int off = 32; off >= 1; off >>= 1) {
    float om = __shfl_xor(mx, off);
    float os = __shfl_xor(se, off);
    float nm = fmaxf(mx, om);
    se = se * __expf(mx - nm) + os * __expf(om - nm);
    mx = nm;
  }
  if (lane == 0) { rmax[(b << 12) + n] = mx; rinv[(b << 12) + n] = 1.f / se; }
}

// ---------------- K5: PAM PV, 16-n tile per block, 512 blocks ----------------
__global__ __launch_bounds__(256) void k_pam_pv(const float* __restrict__ qb,
    const float* __restrict__ kb, const float* __restrict__ vt,
    const float* __restrict__ rmax, const float* __restrict__ rinv,
    const float* __restrict__ sa0, const float* __restrict__ gamma,
    float* __restrict__ sa1) {
  __shared__ float qs[256];        // [ch][16 n]
  __shared__ float ks[1024];       // [ch][64 m]
  __shared__ float pbs[1024];      // [64 m][16 n]
  __shared__ float mxs[16], invs[16];
  __shared__ float obuf[128 * 17];
  int t = threadIdx.x;
  int b = blockIdx.y, n0 = blockIdx.x * 16;
  {
    int ch = t >> 4, r = t & 15;
    qs[t] = qb[((b * 16 + ch) << 12) + n0 + r];
  }
  if (t < 16) { mxs[t] = rmax[(b << 12) + n0 + t]; invs[t] = rinv[(b << 12) + n0 + t]; }
  int cp = t & 63, qd = t >> 6;
  float acc[4][2] = {};
  const float* kpb = kb + ((size_t)b * 16 << 12);
  for (int m0 = 0; m0 < 4096; m0 += 64) {
    for (int idx = t; idx < 1024; idx += 256) {
      int ch = idx >> 6, mm = idx & 63;
      ks[idx] = kpb[(ch << 12) + m0 + mm];
    }
    __syncthreads();
    {
      int m = t >> 2, r0 = (t & 3) * 4;
      float e0 = 0.f, e1 = 0.f, e2 = 0.f, e3 = 0.f;
#pragma unroll
      for (int ch = 0; ch < 16; ++ch) {
        float kk = ks[(ch << 6) + m];
        float4 qv = *(const float4*)(qs + (ch << 4) + r0);
        e0 = fmaf(kk, qv.x, e0); e1 = fmaf(kk, qv.y, e1);
        e2 = fmaf(kk, qv.z, e2); e3 = fmaf(kk, qv.w, e3);
      }
      float4 mv = *(const float4*)(mxs + r0);
      float4 iv = *(const float4*)(invs + r0);
      float4 pv;
      pv.x = __expf(fminf(e0 - mv.x, 0.f)) * iv.x;
      pv.y = __expf(fminf(e1 - mv.y, 0.f)) * iv.y;
      pv.z = __expf(fminf(e2 - mv.z, 0.f)) * iv.z;
      pv.w = __expf(fminf(e3 - mv.w, 0.f)) * iv.w;
      *(float4*)(pbs + (m << 4) + r0) = pv;
    }
    __syncthreads();
    const float* vp = vt + ((size_t)(b * 4096 + m0)) * 128 + (cp << 1);
#pragma unroll 4
    for (int mm = 0; mm < 64; ++mm) {
      float2 vv = *(const float2*)(vp + mm * 128);
      const float* pp = pbs + (mm << 4) + (qd << 2);
      float4 pA = *(const float4*)pp;
      acc[0][0] = fmaf(pA.x, vv.x, acc[0][0]); acc[0][1] = fmaf(pA.x, vv.y, acc[0][1]);
      acc[1][0] = fmaf(pA.y, vv.x, acc[1][0]); acc[1][1] = fmaf(pA.y, vv.y, acc[1][1]);
      acc[2][0] = fmaf(pA.z, vv.x, acc[2][0]); acc[2][1] = fmaf(pA.z, vv.y, acc[2][1]);
      acc[3][0] = fmaf(pA.w, vv.x, acc[3][0]); acc[3][1] = fmaf(pA.w, vv.y, acc[3][1]);
    }
    __syncthreads();
  }
#pragma unroll
  for (int r = 0; r < 4; ++r) {
    obuf[(2 * cp + 0) * 17 + (qd << 2) + r] = acc[r][0];
    obuf[(2 * cp + 1) * 17 + (qd << 2) + r] = acc[r][1];
  }
  __syncthreads();
  float g = gamma[0];
  for (int idx = t; idx < 2048; idx += 256) {
    int c = idx >> 4, nn = idx & 15;
    size_t o = ((size_t)(b * 128 + c) << 12) + n0 + nn;
    sa1[o] = fmaf(g, obuf[c * 17 + nn], sa0[o]);
  }
}

// ---------------- K6a: CAM Gram energy, block per row c, all threads ---------
__global__ __launch_bounds__(256) void k_cam_energy(const float* __restrict__ f,
                                                    float* __restrict__ energy) {
  __shared__ float fc[4096];
  __shared__ float part[256];
  int t = threadIdx.x;
  int c = blockIdx.x, b = blockIdx.y;
  const float* fr = f + ((size_t)(b * 128 + c) << 12);
  for (int i = t; i < 4096; i += 256) fc[i] = fr[i];
  __syncthreads();
  int d = t & 127, seg = t >> 7;
  const float* fd = f + ((size_t)(b * 128 + d) << 12) + seg * 2048;
  const float* fcs = fc + seg * 2048;
  float acc = 0.f;
  for (int nn = 0; nn < 2048; ++nn) acc = fmaf(fcs[nn], fd[nn], acc);
  part[t] = acc;
  __syncthreads();
  if (t < 128)
    energy[((b * 128 + c) << 7) + t] = part[t] + part[t + 128];
}

// ---------------- K6b: CAM softmax row (attn = softmax(rowmax - e)) ----------
__global__ void k_cam_softmax(const float* __restrict__ energy, float* __restrict__ attn) {
  int lane = threadIdx.x;   // 64
  int c = blockIdx.x, b = blockIdx.y;
  const float* e = energy + ((b * 128 + c) << 7);
  float e0 = e[lane], e1 = e[lane + 64];
  float mn = fminf(e0, e1);
#pragma unroll
  for (int off = 32; off >= 1; off >>= 1) mn = fminf(mn, __shfl_xor(mn, off));
  float p0 = __expf(fminf(mn - e0, 0.f)), p1 = __expf(fminf(mn - e1, 0.f));
  float s = p0 + p1;
#pragma unroll
  for (int off = 32; off >= 1; off >>= 1) s += __shfl_xor(s, off);
  float inv = 1.f / s;
  float* a = attn + ((b * 128 + c) << 7);
  a[lane] = p0 * inv;
  a[lane + 64] = p1 * inv;
}

// ---------------- K7: CAM out + residual -------------------------------------
__global__ __launch_bounds__(256) void k_cam_out(const float* __restrict__ f,
    const float* __restrict__ attn, const float* __restrict__ gamma,
    float* __restrict__ sc1) {
  __shared__ float at2[128 * 16];
  int t = threadIdx.x;
  int b = blockIdx.z, c0 = blockIdx.y * 16;
  int n = blockIdx.x * 256 + t;
  for (int idx = t; idx < 2048; idx += 256) {
    int d = idx >> 4, cc = idx & 15;
    at2[idx] = attn[((b * 128 + c0 + cc) << 7) + d];
  }
  __syncthreads();
  float acc[16] = {};
  const float* fb = f + ((size_t)b * 128 << 12) + n;
  for (int d = 0; d < 128; ++d) {
    float fv = fb[d << 12];
    const float* ap = at2 + d * 16;
#pragma unroll
    for (int cc = 0; cc < 16; ++cc) acc[cc] = fmaf(ap[cc], fv, acc[cc]);
  }
  float g = gamma[0];
#pragma unroll
  for (int cc = 0; cc < 16; ++cc) {
    size_t o = ((size_t)(b * 128 + c0 + cc) << 12) + n;
    sc1[o] = fmaf(g, acc[cc], f[o]);
  }
}

// ---------------- K8: BN+ReLU + 1x1 conv 128->512, 16 co per block -----------
__global__ __launch_bounds__(256) void k_branch_out(
    const float* __restrict__ sa1, const float* __restrict__ sc1,
    const float* __restrict__ wa_, const float* __restrict__ ba_,
    const float* __restrict__ ma_, const float* __restrict__ va_,
    const float* __restrict__ wc_, const float* __restrict__ bc_,
    const float* __restrict__ mc_, const float* __restrict__ vc_,
    const float* __restrict__ Wa, const float* __restrict__ Ba,
    const float* __restrict__ Wc, const float* __restrict__ Bc,
    u16* __restrict__ sa2, u16* __restrict__ sc2) {
  int z = blockIdx.z;
  int b = z & 1, br = z >> 1;
  const float* src = br ? sc1 : sa1;
  const float* bw = br ? wc_ : wa_;
  const float* bb = br ? bc_ : ba_;
  const float* bm = br ? mc_ : ma_;
  const float* bvv = br ? vc_ : va_;
  const float* W = br ? Wc : Wa;
  const float* Bs = br ? Bc : Ba;
  u16* dst = br ? sc2 : sa2;
  __shared__ float wl[128 * 16];
  __shared__ float scl[128], shf[128];
  int t = threadIdx.x;
  int co0 = blockIdx.y * 16;
  int n = blockIdx.x * 256 + t;
  if (t < 128) {
    float s = bw[t] * rsqrtf(bvv[t] + 1e-5f);
    scl[t] = s;
    shf[t] = bb[t] - bm[t] * s;
  }
  for (int idx = t; idx < 2048; idx += 256) {
    int ci = idx >> 4, cc = idx & 15;
    wl[idx] = W[(co0 + cc) * 128 + ci];
  }
  __syncthreads();
  float acc[16] = {};
  const float* sp = src + ((size_t)b * 128 << 12) + n;
  for (int ci = 0; ci < 128; ++ci) {
    float xv = fmaxf(fmaf(sp[ci << 12], scl[ci], shf[ci]), 0.f);
    const float* wp = wl + ci * 16;
    float4 w0 = *(const float4*)wp;
    float4 w1 = *(const float4*)(wp + 4);
    float4 w2 = *(const float4*)(wp + 8);
    float4 w3 = *(const float4*)(wp + 12);
    acc[0] = fmaf(w0.x, xv, acc[0]);  acc[1] = fmaf(w0.y, xv, acc[1]);
    acc[2] = fmaf(w0.z, xv, acc[2]);  acc[3] = fmaf(w0.w, xv, acc[3]);
    acc[4] = fmaf(w1.x, xv, acc[4]);  acc[5] = fmaf(w1.y, xv, acc[5]);
    acc[6] = fmaf(w1.z, xv, acc[6]);  acc[7] = fmaf(w1.w, xv, acc[7]);
    acc[8] = fmaf(w2.x, xv, acc[8]);  acc[9] = fmaf(w2.y, xv, acc[9]);
    acc[10] = fmaf(w2.z, xv, acc[10]); acc[11] = fmaf(w2.w, xv, acc[11]);
    acc[12] = fmaf(w3.x, xv, acc[12]); acc[13] = fmaf(w3.y, xv, acc[13]);
    acc[14] = fmaf(w3.z, xv, acc[14]); acc[15] = fmaf(w3.w, xv, acc[15]);
  }
#pragma unroll
  for (int cc = 0; cc < 16; ++cc) {
    dst[((size_t)(b * 512 + co0 + cc) << 12) + n] = f2bf(acc[cc] + Bs[co0 + cc]);
  }
}

// ---------------- K9a: fusion + partial class-head sums (8-way c split) ------
__global__ __launch_bounds__(256) void k_heads(const u16* __restrict__ sa2,
    const u16* __restrict__ sc2,
    const float* __restrict__ wf, const float* __restrict__ wa, const float* __restrict__ wc,
    float* __restrict__ outFusion, float* __restrict__ clsacc) {
  __shared__ float lw[3 * 5 * 64];
  int t = threadIdx.x;
  int b = blockIdx.y, co0 = blockIdx.z * 64;
  int n = blockIdx.x * 256 + t;
  for (int idx = t; idx < 960; idx += 256) {
    int arr = idx / 320, rest = idx - arr * 320;
    int cls = rest >> 6, cc = rest & 63;
    const float* w = arr == 0 ? wf : (arr == 1 ? wa : wc);
    lw[idx] = w[cls * 512 + co0 + cc];
  }
  __syncthreads();
  float af[5] = {}, aa[5] = {}, ac[5] = {};
  for (int cc = 0; cc < 64; ++cc) {
    size_t o = ((size_t)(b * 512 + co0 + cc) << 12) + n;
    float a = bf2f(sa2[o]), c = bf2f(sc2[o]);
    float s = a + c;
    outFusion[o] = s;
#pragma unroll
    for (int cls = 0; cls < 5; ++cls) {
      af[cls] = fmaf(lw[0 * 320 + cls * 64 + cc], s, af[cls]);
      aa[cls] = fmaf(lw[1 * 320 + cls * 64 + cc], a, aa[cls]);
      ac[cls] = fmaf(lw[2 * 320 + cls * 64 + cc], c, ac[cls]);
    }
  }
#pragma unroll
  for (int cls = 0; cls < 5; ++cls) {
    int o = ((b * 5 + cls) << 12) + n;
    atomicAdd(&clsacc[o], af[cls]);
    atomicAdd(&clsacc[40960 + o], aa[cls]);
    atomicAdd(&clsacc[81920 + o], ac[cls]);
  }
}

// ---------------- K9b: add bias, f32 out -------------------------------------
__global__ void k_heads_final(const float* __restrict__ clsacc,
    const float* __restrict__ bf_, const float* __restrict__ ba_,
    const float* __restrict__ bc_, float* __restrict__ outCls) {
  int idx = blockIdx.x * 256 + threadIdx.x;   // 122880
  int arr = idx / 40960;
  int rest = idx - arr * 40960;
  int cls = (rest >> 12) % 5;
  const float* bp = arr == 0 ? bf_ : (arr == 1 ? ba_ : bc_);
  outCls[idx] = clsacc[idx] + bp[cls];
}

extern "C" void kernel_launch(void* const* d_in, const int* in_sizes, int n_in,
                              void* d_out, int out_size, void* d_ws, size_t ws_size,
                              hipStream_t stream) {
  (void)in_sizes; (void)n_in; (void)out_size; (void)ws_size;
  const float* x      = (const float*)d_in[0];
  const float* bnaw   = (const float*)d_in[1];
  const float* bnab   = (const float*)d_in[2];
  const float* bnam   = (const float*)d_in[3];
  const float* bnav   = (const float*)d_in[4];
  const float* convaw = (const float*)d_in[5];
  const float* bncw   = (const float*)d_in[6];
  const float* bncb   = (const float*)d_in[7];
  const float* bncm   = (const float*)d_in[8];
  const float* bncv   = (const float*)d_in[9];
  const float* convcw = (const float*)d_in[10];
  const float* pqw    = (const float*)d_in[11];
  const float* pqb    = (const float*)d_in[12];
  const float* pkw    = (const float*)d_in[13];
  const float* pkb    = (const float*)d_in[14];
  const float* pvw    = (const float*)d_in[15];
  const float* pvb    = (const float*)d_in[16];
  const float* pgam   = (const float*)d_in[17];
  const float* cgam   = (const float*)d_in[18];
  const float* bna1w  = (const float*)d_in[19];
  const float* bna1b  = (const float*)d_in[20];
  const float* bna1m  = (const float*)d_in[21];
  const float* bna1v  = (const float*)d_in[22];
  const float* conva1w = (const float*)d_in[23];
  const float* conva1b = (const float*)d_in[24];
  const float* bnc1w  = (const float*)d_in[25];
  const float* bnc1b  = (const float*)d_in[26];
  const float* bnc1m  = (const float*)d_in[27];
  const float* bnc1v  = (const float*)d_in[28];
  const float* convc1w = (const float*)d_in[29];
  const float* convc1b = (const float*)d_in[30];
  const float* outaw  = (const float*)d_in[31];
  const float* outab  = (const float*)d_in[32];
  const float* outcw  = (const float*)d_in[33];
  const float* outcb  = (const float*)d_in[34];
  const float* outfw  = (const float*)d_in[35];
  const float* outfb  = (const float*)d_in[36];

  char* wsb = (char*)d_ws;
  size_t off = 0;
  auto take = [&](size_t bytes) -> void* {
    void* p = wsb + off;
    off += (bytes + 255) & ~(size_t)255;
    return p;
  };
  float* wvT   = (float*)take((size_t)128 * 128 * 4);
  u16*   Wb    = (u16*)take((size_t)2 * 128 * 9 * 512 * 2);
  u16*   xa16  = (u16*)take((size_t)2 * 512 * 4096 * 2);
  u16*   xcb16 = (u16*)take((size_t)2 * 512 * 4096 * 2);
  float* sa0   = (float*)take((size_t)2 * 128 * 4096 * 4);
  float* sc0   = (float*)take((size_t)2 * 128 * 4096 * 4);
  float* qb    = (float*)take((size_t)2 * 16 * 4096 * 4);
  float* kbuf  = (float*)take((size_t)2 * 16 * 4096 * 4);
  float* vt    = (float*)take((size_t)2 * 4096 * 128 * 4);
  float* rmax  = (float*)take((size_t)2 * 4096 * 4);
  float* rinv  = (float*)take((size_t)2 * 4096 * 4);
  float* sa1   = (float*)take((size_t)2 * 128 * 4096 * 4);
  float* sc1   = (float*)take((size_t)2 * 128 * 4096 * 4);
  float* energy = (float*)take((size_t)2 * 128 * 128 * 4);
  float* attn  = (float*)take((size_t)2 * 128 * 128 * 4);
  u16*   sa2   = (u16*)take((size_t)2 * 512 * 4096 * 2);
  u16*   sc2   = (u16*)take((size_t)2 * 512 * 4096 * 2);
  float* clsacc = (float*)take((size_t)3 * 2 * 5 * 4096 * 4);

  float* outF = (float*)d_out;
  float* outCls = outF + (size_t)2 * 512 * 4096;

  hipMemsetAsync(clsacc, 0, (size_t)3 * 2 * 5 * 4096 * 4, stream);

  k_prep_wv<<<64, 256, 0, stream>>>(pvw, wvT);
  k_prep_w<<<4608, 256, 0, stream>>>(convaw, convcw, Wb);
  k_bnrelu2<<<4096, 256, 0, stream>>>(x, bnaw, bnab, bnam, bnav,
                                      bncw, bncb, bncm, bncv, xa16, xcb16);
  k_conv3m<<<dim3(64, 4, 4), 256, 0, stream>>>(xa16, xcb16, Wb, sa0, sc0);
  k_qk<<<dim3(16, 32, 2), 256, 0, stream>>>(sa0, pqw, pqb, pkw, pkb, qb, kbuf);
  k_vt<<<dim3(2048, 2), 256, 0, stream>>>(sa0, wvT, pvb, vt);
  k_pam_stats<<<dim3(1024, 2), 256, 0, stream>>>(qb, kbuf, rmax, rinv);
  k_pam_pv<<<dim3(256, 2), 256, 0, stream>>>(qb, kbuf, vt, rmax, rinv, sa0, pgam, sa1);
  k_cam_energy<<<dim3(128, 2), 256, 0, stream>>>(sc0, energy);
  k_cam_softmax<<<dim3(128, 2), 64, 0, stream>>>(energy, attn);
  k_cam_out<<<dim3(16, 8, 2), 256, 0, stream>>>(sc0, attn, cgam, sc1);
  k_branch_out<<<dim3(16, 32, 4), 256, 0, stream>>>(sa1, sc1,
      bna1w, bna1b, bna1m, bna1v, bnc1w, bnc1b, bnc1m, bnc1v,
      conva1w, conva1b, convc1w, convc1b, sa2, sc2);
  k_heads<<<dim3(16, 2, 8), 256, 0, stream>>>(sa2, sc2, outfw, outaw, outcw, outF, clsacc);
  k_heads_final<<<480, 256, 0, stream>>>(clsacc, outfb, outab, outcb, outCls);
}

// Round 11
// 626.758 us; speedup vs baseline: 2.6242x; 1.4616x over previous
//
#include <hip/hip_runtime.h>

using u16 = unsigned short;
using short8 = __attribute__((ext_vector_type(8))) short;
using f32x4 = __attribute__((ext_vector_type(4))) float;

struct alignas(8) U16x4 { u16 x, y, z, w; };

__device__ __forceinline__ float bf2f(u16 u) {
  return __uint_as_float(((unsigned int)u) << 16);
}
__device__ __forceinline__ u16 f2bf(float f) {
  unsigned int u = __float_as_uint(f);
  unsigned int r = u + 0x7FFFu + ((u >> 16) & 1u);
  return (u16)(r >> 16);
}

// ---------------- K0a: transpose pam_v_w [c][ci] -> wvT [ci][c] --------------
__global__ void k_prep_wv(const float* __restrict__ wv, float* __restrict__ wvT) {
  int idx = blockIdx.x * 256 + threadIdx.x;   // 16384
  int ci = idx >> 7, c = idx & 127;
  wvT[ci * 128 + c] = wv[c * 128 + ci];
}

// ---------------- K0b: conv weights -> bf16, tap-major Wb[br][co][tap][ci] ---
__global__ void k_prep_w(const float* __restrict__ wa, const float* __restrict__ wc,
                         u16* __restrict__ Wb) {
  int idx = blockIdx.x * 256 + threadIdx.x;   // 2*128*9*512 = 1179648
  int ci = idx & 511;
  int rest = idx >> 9;          // br*128*9 + co*9 + tap
  int tap = rest % 9;
  int rest2 = rest / 9;         // br*128 + co
  int co = rest2 & 127, br = rest2 >> 7;
  const float* w = br ? wc : wa;
  Wb[idx] = f2bf(w[co * 4608 + ci * 9 + tap]);
}

// ---------------- K1: BN+ReLU for both branches, bf16 out --------------------
__global__ void k_bnrelu2(const float* __restrict__ x,
    const float* __restrict__ wa, const float* __restrict__ ba,
    const float* __restrict__ ma, const float* __restrict__ va,
    const float* __restrict__ wc, const float* __restrict__ bc,
    const float* __restrict__ mc, const float* __restrict__ vc,
    u16* __restrict__ xa16, u16* __restrict__ xcb16) {
  int i4 = (blockIdx.x * 256 + threadIdx.x) * 4;   // over 2*512*4096
  int c = (i4 >> 12) & 511;
  float sA = wa[c] * rsqrtf(va[c] + 1e-5f);
  float bA = ba[c] - ma[c] * sA;
  float sC = wc[c] * rsqrtf(vc[c] + 1e-5f);
  float bC = bc[c] - mc[c] * sC;
  float4 xv = *(const float4*)(x + i4);
  U16x4 oa, oc;
  oa.x = f2bf(fmaxf(xv.x * sA + bA, 0.f)); oc.x = f2bf(fmaxf(xv.x * sC + bC, 0.f));
  oa.y = f2bf(fmaxf(xv.y * sA + bA, 0.f)); oc.y = f2bf(fmaxf(xv.y * sC + bC, 0.f));
  oa.z = f2bf(fmaxf(xv.z * sA + bA, 0.f)); oc.z = f2bf(fmaxf(xv.z * sC + bC, 0.f));
  oa.w = f2bf(fmaxf(xv.w * sA + bA, 0.f)); oc.w = f2bf(fmaxf(xv.w * sC + bC, 0.f));
  *(U16x4*)(xa16 + i4) = oa;
  *(U16x4*)(xcb16 + i4) = oc;
}

// ---------------- K2: 3x3 conv via MFMA implicit GEMM ------------------------
__global__ __launch_bounds__(256) void k_conv3m(
    const u16* __restrict__ xa16, const u16* __restrict__ xcb16,
    const u16* __restrict__ Wb,
    float* __restrict__ sa0, float* __restrict__ sc0) {
  __shared__ u16 xl[64 * 40];   // [w][ci_l], stride 40 u16
  int t = threadIdx.x;
  int h = blockIdx.x;
  int co0 = blockIdx.y * 32;
  int z = blockIdx.z;
  int b = z & 1, br = z >> 1;
  const u16* xb = (br ? xcb16 : xa16) + ((size_t)b * 512 << 12);
  const short* wbase = (const short*)(Wb + (size_t)br * 128 * 9 * 512);
  float* out = br ? sc0 : sa0;

  int lane = t & 63, wave = t >> 6;
  int coh = (wave >> 1) << 4;     // 0 or 16
  int nh  = (wave & 1) << 5;      // 0 or 32
  int mi = lane & 15, quad = lane >> 4;

  int ws_ = t & 63;               // staging w (0..63)
  int cig = (t >> 6) << 3;        // staging ci_l base: 0,8,16,24

  f32x4 acc0 = {0.f, 0.f, 0.f, 0.f};
  f32x4 acc1 = {0.f, 0.f, 0.f, 0.f};

  const short* wrow = wbase + ((size_t)(co0 + coh + mi) * 9) * 512;

  for (int tap = 0; tap < 9; ++tap) {
    int dh = tap / 3 - 1, dw = tap % 3 - 1;
    int hh = h + dh;
    if (hh < 0 || hh > 63) continue;          // block-uniform skip
    int wp = ws_ + dw;
    bool valid = (wp >= 0) && (wp < 64);
    const u16* srow = xb + (hh << 6) + wp;
    const short* wtap = wrow + (size_t)tap * 512;
    for (int ci0 = 0; ci0 < 512; ci0 += 32) {
      short8 v;
      const u16* sp = srow + ((size_t)(ci0 + cig) << 12);
#pragma unroll
      for (int j = 0; j < 8; ++j)
        v[j] = valid ? (short)sp[(size_t)j << 12] : (short)0;
      __syncthreads();
      *(short8*)(xl + ws_ * 40 + cig) = v;
      __syncthreads();
      short8 a = *(const short8*)(wtap + ci0 + quad * 8);
      short8 b0 = *(const short8*)(xl + (nh + mi) * 40 + quad * 8);
      short8 b1 = *(const short8*)(xl + (nh + 16 + mi) * 40 + quad * 8);
      acc0 = __builtin_amdgcn_mfma_f32_16x16x32_bf16(a, b0, acc0, 0, 0, 0);
      acc1 = __builtin_amdgcn_mfma_f32_16x16x32_bf16(a, b1, acc1, 0, 0, 0);
    }
  }
#pragma unroll
  for (int r = 0; r < 4; ++r) {
    int co = co0 + coh + quad * 4 + r;
    size_t o = ((size_t)(b * 128 + co) << 12) + (h << 6) + nh + mi;
    out[o] = acc0[r];
    out[o + 16] = acc1[r];
  }
}

// ---------------- K3a: 1x1 conv -> q,k ([b][16][4096] f32) -------------------
__global__ void k_qk(const float* __restrict__ sa0,
    const float* __restrict__ wq, const float* __restrict__ bq,
    const float* __restrict__ wk, const float* __restrict__ bk,
    float* __restrict__ qb, float* __restrict__ kb) {
  int n = blockIdx.x * 256 + threadIdx.x;
  int co = blockIdx.y, b = blockIdx.z;
  const float* w; float* dst; float bias;
  if (co < 16) { w = wq + co * 128; bias = bq[co]; dst = qb + ((b * 16 + co) << 12); }
  else { int c2 = co - 16; w = wk + c2 * 128; bias = bk[c2]; dst = kb + ((b * 16 + c2) << 12); }
  const float* s = sa0 + ((size_t)b * 128 << 12) + n;
  float acc = bias;
  for (int ci = 0; ci < 128; ++ci) acc = fmaf(w[ci], s[ci << 12], acc);
  dst[n] = acc;
}

// ---------------- K3b: 1x1 conv -> v, bf16, layout vt16[b][c][n] -------------
__global__ __launch_bounds__(256) void k_vt(const float* __restrict__ sa0,
    const float* __restrict__ wvT, const float* __restrict__ bv,
    u16* __restrict__ vt16) {
  int t = threadIdx.x;
  int n = blockIdx.x * 256 + t;        // 16 n-blocks
  int c0 = blockIdx.y * 8;             // 16 c-groups
  int b = blockIdx.z;
  const float* s = sa0 + ((size_t)b * 128 << 12) + n;
  float acc[8];
#pragma unroll
  for (int c = 0; c < 8; ++c) acc[c] = bv[c0 + c];
  for (int ci = 0; ci < 128; ++ci) {
    float xv = s[ci << 12];
    const float* wp = wvT + ci * 128 + c0;
#pragma unroll
    for (int c = 0; c < 8; ++c) acc[c] = fmaf(wp[c], xv, acc[c]);
  }
#pragma unroll
  for (int c = 0; c < 8; ++c)
    vt16[((size_t)(b * 128 + c0 + c) << 12) + n] = f2bf(acc[c]);
}

// ---------------- K4: PAM softmax row stats (max, 1/sum) ---------------------
__global__ __launch_bounds__(256) void k_pam_stats(const float* __restrict__ qb,
    const float* __restrict__ kb, float* __restrict__ rmax, float* __restrict__ rinv) {
  int t = threadIdx.x, lane = t & 63, wid = t >> 6;
  int b = blockIdx.y;
  int n = blockIdx.x * 4 + wid;
  float qreg[16];
  const float* qp = qb + ((size_t)b * 16 << 12) + n;
#pragma unroll
  for (int ch = 0; ch < 16; ++ch) qreg[ch] = qp[ch << 12];
  const float* kp = kb + ((size_t)b * 16 << 12);
  float mx = -1e30f, se = 0.f;
  for (int m = lane; m < 4096; m += 64) {
    float e = 0.f;
#pragma unroll
    for (int ch = 0; ch < 16; ++ch) e = fmaf(qreg[ch], kp[(ch << 12) + m], e);
    float nm = fmaxf(mx, e);
    se = se * __expf(mx - nm) + __expf(e - nm);
    mx = nm;
  }
#pragma unroll
  for (int off = 32; off >= 1; off >>= 1) {
    float om = __shfl_xor(mx, off);
    float os = __shfl_xor(se, off);
    float nm = fmaxf(mx, om);
    se = se * __expf(mx - nm) + os * __expf(om - nm);
    mx = nm;
  }
  if (lane == 0) { rmax[(b << 12) + n] = mx; rinv[(b << 12) + n] = 1.f / se; }
}

// ---------------- K5: PAM PV via MFMA, 16-n tile per block -------------------
// 256 thr = 4 waves; wave w covers c in [32w, 32w+32); K loop over m (64/iter).
__global__ __launch_bounds__(256) void k_pam_pv(const float* __restrict__ qb,
    const float* __restrict__ kb, const u16* __restrict__ vt16,
    const float* __restrict__ rmax, const float* __restrict__ rinv,
    const float* __restrict__ sa0, const float* __restrict__ gamma,
    float* __restrict__ sa1) {
  __shared__ float qs[256];       // [ch][16 n]
  __shared__ float ks[1024];      // [ch][64 m]
  __shared__ u16 pL[16 * 72];     // [n][64 m] bf16, row stride 72 (144B, 16B-mult)
  __shared__ float mxs[16], invs[16];
  __shared__ float obuf[128 * 17];
  int t = threadIdx.x;
  int b = blockIdx.y, n0 = blockIdx.x * 16;
  {
    int ch = t >> 4, r = t & 15;
    qs[t] = qb[((b * 16 + ch) << 12) + n0 + r];
  }
  if (t < 16) { mxs[t] = rmax[(b << 12) + n0 + t]; invs[t] = rinv[(b << 12) + n0 + t]; }
  int lane = t & 63, wave = t >> 6;
  int mi = lane & 15, quad = lane >> 4;
  int c0 = wave * 32;
  f32x4 acc0 = {0.f, 0.f, 0.f, 0.f};
  f32x4 acc1 = {0.f, 0.f, 0.f, 0.f};
  const float* kpb = kb + ((size_t)b * 16 << 12);
  const u16* vb = vt16 + ((size_t)b * 128 << 12);
  // stage first k tile
  for (int idx = t; idx < 1024; idx += 256) {
    int ch = idx >> 6, mm = idx & 63;
    ks[idx] = kpb[(ch << 12) + mm];
  }
  __syncthreads();
  int pm = t >> 2, pr0 = (t & 3) * 4;
  for (int m0 = 0; m0 < 4096; m0 += 64) {
    // p-compute: e = q.k, p = exp(e-mx)*rinv -> pL bf16 [n][m]
    {
      float e0 = 0.f, e1 = 0.f, e2 = 0.f, e3 = 0.f;
#pragma unroll
      for (int ch = 0; ch < 16; ++ch) {
        float kk = ks[(ch << 6) + pm];
        float4 qv = *(const float4*)(qs + (ch << 4) + pr0);
        e0 = fmaf(kk, qv.x, e0); e1 = fmaf(kk, qv.y, e1);
        e2 = fmaf(kk, qv.z, e2); e3 = fmaf(kk, qv.w, e3);
      }
      float4 mv = *(const float4*)(mxs + pr0);
      float4 iv = *(const float4*)(invs + pr0);
      pL[(pr0 + 0) * 72 + pm] = f2bf(__expf(fminf(e0 - mv.x, 0.f)) * iv.x);
      pL[(pr0 + 1) * 72 + pm] = f2bf(__expf(fminf(e1 - mv.y, 0.f)) * iv.y);
      pL[(pr0 + 2) * 72 + pm] = f2bf(__expf(fminf(e2 - mv.z, 0.f)) * iv.z);
      pL[(pr0 + 3) * 72 + pm] = f2bf(__expf(fminf(e3 - mv.w, 0.f)) * iv.w);
    }
    __syncthreads();
    // stage next k tile (overlaps MFMA; different array than pL)
    if (m0 + 64 < 4096) {
      int m1 = m0 + 64;
      for (int idx = t; idx < 1024; idx += 256) {
        int ch = idx >> 6, mm = idx & 63;
        ks[idx] = kpb[(ch << 12) + m1 + mm];
      }
    }
    // MFMA: acc[c][n] += vt16[c][m] * p[m][n]
#pragma unroll
    for (int kk = 0; kk < 64; kk += 32) {
      short8 bfrag = *(const short8*)(pL + mi * 72 + kk + quad * 8);
      const u16* ap = vb + ((size_t)(c0 + mi) << 12) + m0 + kk + quad * 8;
      short8 a0 = *(const short8*)ap;
      short8 a1 = *(const short8*)(ap + ((size_t)16 << 12));
      acc0 = __builtin_amdgcn_mfma_f32_16x16x32_bf16(a0, bfrag, acc0, 0, 0, 0);
      acc1 = __builtin_amdgcn_mfma_f32_16x16x32_bf16(a1, bfrag, acc1, 0, 0, 0);
    }
    __syncthreads();
  }
  // D layout: col(n)=lane&15, row=quad*4+r
#pragma unroll
  for (int r = 0; r < 4; ++r) {
    obuf[(c0 + quad * 4 + r) * 17 + mi] = acc0[r];
    obuf[(c0 + 16 + quad * 4 + r) * 17 + mi] = acc1[r];
  }
  __syncthreads();
  float g = gamma[0];
  for (int idx = t; idx < 2048; idx += 256) {
    int c = idx >> 4, nn = idx & 15;
    size_t o = ((size_t)(b * 128 + c) << 12) + n0 + nn;
    sa1[o] = fmaf(g, obuf[c * 17 + nn], sa0[o]);
  }
}

// ---------------- K6a: CAM Gram energy, block per row c, all threads ---------
__global__ __launch_bounds__(256) void k_cam_energy(const float* __restrict__ f,
                                                    float* __restrict__ energy) {
  __shared__ float fc[4096];
  __shared__ float part[256];
  int t = threadIdx.x;
  int c = blockIdx.x, b = blockIdx.y;
  const float* fr = f + ((size_t)(b * 128 + c) << 12);
  for (int i = t; i < 4096; i += 256) fc[i] = fr[i];
  __syncthreads();
  int d = t & 127, seg = t >> 7;
  const float* fd = f + ((size_t)(b * 128 + d) << 12) + seg * 2048;
  const float* fcs = fc + seg * 2048;
  float acc = 0.f;
  for (int nn = 0; nn < 2048; ++nn) acc = fmaf(fcs[nn], fd[nn], acc);
  part[t] = acc;
  __syncthreads();
  if (t < 128)
    energy[((b * 128 + c) << 7) + t] = part[t] + part[t + 128];
}

// ---------------- K6b: CAM softmax row (attn = softmax(rowmax - e)) ----------
__global__ void k_cam_softmax(const float* __restrict__ energy, float* __restrict__ attn) {
  int lane = threadIdx.x;   // 64
  int c = blockIdx.x, b = blockIdx.y;
  const float* e = energy + ((b * 128 + c) << 7);
  float e0 = e[lane], e1 = e[lane + 64];
  float mn = fminf(e0, e1);
#pragma unroll
  for (int off = 32; off >= 1; off >>= 1) mn = fminf(mn, __shfl_xor(mn, off));
  float p0 = __expf(fminf(mn - e0, 0.f)), p1 = __expf(fminf(mn - e1, 0.f));
  float s = p0 + p1;
#pragma unroll
  for (int off = 32; off >= 1; off >>= 1) s += __shfl_xor(s, off);
  float inv = 1.f / s;
  float* a = attn + ((b * 128 + c) << 7);
  a[lane] = p0 * inv;
  a[lane + 64] = p1 * inv;
}

// ---------------- K7: CAM out + residual -------------------------------------
__global__ __launch_bounds__(256) void k_cam_out(const float* __restrict__ f,
    const float* __restrict__ attn, const float* __restrict__ gamma,
    float* __restrict__ sc1) {
  __shared__ float at2[128 * 16];
  int t = threadIdx.x;
  int b = blockIdx.z, c0 = blockIdx.y * 16;
  int n = blockIdx.x * 256 + t;
  for (int idx = t; idx < 2048; idx += 256) {
    int d = idx >> 4, cc = idx & 15;
    at2[idx] = attn[((b * 128 + c0 + cc) << 7) + d];
  }
  __syncthreads();
  float acc[16] = {};
  const float* fb = f + ((size_t)b * 128 << 12) + n;
  for (int d = 0; d < 128; ++d) {
    float fv = fb[d << 12];
    const float* ap = at2 + d * 16;
#pragma unroll
    for (int cc = 0; cc < 16; ++cc) acc[cc] = fmaf(ap[cc], fv, acc[cc]);
  }
  float g = gamma[0];
#pragma unroll
  for (int cc = 0; cc < 16; ++cc) {
    size_t o = ((size_t)(b * 128 + c0 + cc) << 12) + n;
    sc1[o] = fmaf(g, acc[cc], f[o]);
  }
}

// ---------------- K8: BN+ReLU + 1x1 conv 128->512, 16 co per block -----------
__global__ __launch_bounds__(256) void k_branch_out(
    const float* __restrict__ sa1, const float* __restrict__ sc1,
    const float* __restrict__ wa_, const float* __restrict__ ba_,
    const float* __restrict__ ma_, const float* __restrict__ va_,
    const float* __restrict__ wc_, const float* __restrict__ bc_,
    const float* __restrict__ mc_, const float* __restrict__ vc_,
    const float* __restrict__ Wa, const float* __restrict__ Ba,
    const float* __restrict__ Wc, const float* __restrict__ Bc,
    u16* __restrict__ sa2, u16* __restrict__ sc2) {
  int z = blockIdx.z;
  int b = z & 1, br = z >> 1;
  const float* src = br ? sc1 : sa1;
  const float* bw = br ? wc_ : wa_;
  const float* bb = br ? bc_ : ba_;
  const float* bm = br ? mc_ : ma_;
  const float* bvv = br ? vc_ : va_;
  const float* W = br ? Wc : Wa;
  const float* Bs = br ? Bc : Ba;
  u16* dst = br ? sc2 : sa2;
  __shared__ float wl[128 * 16];
  __shared__ float scl[128], shf[128];
  int t = threadIdx.x;
  int co0 = blockIdx.y * 16;
  int n = blockIdx.x * 256 + t;
  if (t < 128) {
    float s = bw[t] * rsqrtf(bvv[t] + 1e-5f);
    scl[t] = s;
    shf[t] = bb[t] - bm[t] * s;
  }
  for (int idx = t; idx < 2048; idx += 256) {
    int ci = idx >> 4, cc = idx & 15;
    wl[idx] = W[(co0 + cc) * 128 + ci];
  }
  __syncthreads();
  float acc[16] = {};
  const float* sp = src + ((size_t)b * 128 << 12) + n;
  for (int ci = 0; ci < 128; ++ci) {
    float xv = fmaxf(fmaf(sp[ci << 12], scl[ci], shf[ci]), 0.f);
    const float* wp = wl + ci * 16;
    float4 w0 = *(const float4*)wp;
    float4 w1 = *(const float4*)(wp + 4);
    float4 w2 = *(const float4*)(wp + 8);
    float4 w3 = *(const float4*)(wp + 12);
    acc[0] = fmaf(w0.x, xv, acc[0]);  acc[1] = fmaf(w0.y, xv, acc[1]);
    acc[2] = fmaf(w0.z, xv, acc[2]);  acc[3] = fmaf(w0.w, xv, acc[3]);
    acc[4] = fmaf(w1.x, xv, acc[4]);  acc[5] = fmaf(w1.y, xv, acc[5]);
    acc[6] = fmaf(w1.z, xv, acc[6]);  acc[7] = fmaf(w1.w, xv, acc[7]);
    acc[8] = fmaf(w2.x, xv, acc[8]);  acc[9] = fmaf(w2.y, xv, acc[9]);
    acc[10] = fmaf(w2.z, xv, acc[10]); acc[11] = fmaf(w2.w, xv, acc[11]);
    acc[12] = fmaf(w3.x, xv, acc[12]); acc[13] = fmaf(w3.y, xv, acc[13]);
    acc[14] = fmaf(w3.z, xv, acc[14]); acc[15] = fmaf(w3.w, xv, acc[15]);
  }
#pragma unroll
  for (int cc = 0; cc < 16; ++cc) {
    dst[((size_t)(b * 512 + co0 + cc) << 12) + n] = f2bf(acc[cc] + Bs[co0 + cc]);
  }
}

// ---------------- K9a: fusion + partial class-head sums (8-way c split) ------
__global__ __launch_bounds__(256) void k_heads(const u16* __restrict__ sa2,
    const u16* __restrict__ sc2,
    const float* __restrict__ wf, const float* __restrict__ wa, const float* __restrict__ wc,
    float* __restrict__ outFusion, float* __restrict__ clsacc) {
  __shared__ float lw[3 * 5 * 64];
  int t = threadIdx.x;
  int b = blockIdx.y, co0 = blockIdx.z * 64;
  int n = blockIdx.x * 256 + t;
  for (int idx = t; idx < 960; idx += 256) {
    int arr = idx / 320, rest = idx - arr * 320;
    int cls = rest >> 6, cc = rest & 63;
    const float* w = arr == 0 ? wf : (arr == 1 ? wa : wc);
    lw[idx] = w[cls * 512 + co0 + cc];
  }
  __syncthreads();
  float af[5] = {}, aa[5] = {}, ac[5] = {};
  for (int cc = 0; cc < 64; ++cc) {
    size_t o = ((size_t)(b * 512 + co0 + cc) << 12) + n;
    float a = bf2f(sa2[o]), c = bf2f(sc2[o]);
    float s = a + c;
    outFusion[o] = s;
#pragma unroll
    for (int cls = 0; cls < 5; ++cls) {
      af[cls] = fmaf(lw[0 * 320 + cls * 64 + cc], s, af[cls]);
      aa[cls] = fmaf(lw[1 * 320 + cls * 64 + cc], a, aa[cls]);
      ac[cls] = fmaf(lw[2 * 320 + cls * 64 + cc], c, ac[cls]);
    }
  }
#pragma unroll
  for (int cls = 0; cls < 5; ++cls) {
    int o = ((b * 5 + cls) << 12) + n;
    atomicAdd(&clsacc[o], af[cls]);
    atomicAdd(&clsacc[40960 + o], aa[cls]);
    atomicAdd(&clsacc[81920 + o], ac[cls]);
  }
}

// ---------------- K9b: add bias, f32 out -------------------------------------
__global__ void k_heads_final(const float* __restrict__ clsacc,
    const float* __restrict__ bf_, const float* __restrict__ ba_,
    const float* __restrict__ bc_, float* __restrict__ outCls) {
  int idx = blockIdx.x * 256 + threadIdx.x;   // 122880
  int arr = idx / 40960;
  int rest = idx - arr * 40960;
  int cls = (rest >> 12) % 5;
  const float* bp = arr == 0 ? bf_ : (arr == 1 ? ba_ : bc_);
  outCls[idx] = clsacc[idx] + bp[cls];
}

extern "C" void kernel_launch(void* const* d_in, const int* in_sizes, int n_in,
                              void* d_out, int out_size, void* d_ws, size_t ws_size,
                              hipStream_t stream) {
  (void)in_sizes; (void)n_in; (void)out_size; (void)ws_size;
  const float* x      = (const float*)d_in[0];
  const float* bnaw   = (const float*)d_in[1];
  const float* bnab   = (const float*)d_in[2];
  const float* bnam   = (const float*)d_in[3];
  const float* bnav   = (const float*)d_in[4];
  const float* convaw = (const float*)d_in[5];
  const float* bncw   = (const float*)d_in[6];
  const float* bncb   = (const float*)d_in[7];
  const float* bncm   = (const float*)d_in[8];
  const float* bncv   = (const float*)d_in[9];
  const float* convcw = (const float*)d_in[10];
  const float* pqw    = (const float*)d_in[11];
  const float* pqb    = (const float*)d_in[12];
  const float* pkw    = (const float*)d_in[13];
  const float* pkb    = (const float*)d_in[14];
  const float* pvw    = (const float*)d_in[15];
  const float* pvb    = (const float*)d_in[16];
  const float* pgam   = (const float*)d_in[17];
  const float* cgam   = (const float*)d_in[18];
  const float* bna1w  = (const float*)d_in[19];
  const float* bna1b  = (const float*)d_in[20];
  const float* bna1m  = (const float*)d_in[21];
  const float* bna1v  = (const float*)d_in[22];
  const float* conva1w = (const float*)d_in[23];
  const float* conva1b = (const float*)d_in[24];
  const float* bnc1w  = (const float*)d_in[25];
  const float* bnc1b  = (const float*)d_in[26];
  const float* bnc1m  = (const float*)d_in[27];
  const float* bnc1v  = (const float*)d_in[28];
  const float* convc1w = (const float*)d_in[29];
  const float* convc1b = (const float*)d_in[30];
  const float* outaw  = (const float*)d_in[31];
  const float* outab  = (const float*)d_in[32];
  const float* outcw  = (const float*)d_in[33];
  const float* outcb  = (const float*)d_in[34];
  const float* outfw  = (const float*)d_in[35];
  const float* outfb  = (const float*)d_in[36];

  char* wsb = (char*)d_ws;
  size_t off = 0;
  auto take = [&](size_t bytes) -> void* {
    void* p = wsb + off;
    off += (bytes + 255) & ~(size_t)255;
    return p;
  };
  float* wvT   = (float*)take((size_t)128 * 128 * 4);
  u16*   Wb    = (u16*)take((size_t)2 * 128 * 9 * 512 * 2);
  u16*   xa16  = (u16*)take((size_t)2 * 512 * 4096 * 2);
  u16*   xcb16 = (u16*)take((size_t)2 * 512 * 4096 * 2);
  float* sa0   = (float*)take((size_t)2 * 128 * 4096 * 4);
  float* sc0   = (float*)take((size_t)2 * 128 * 4096 * 4);
  float* qb    = (float*)take((size_t)2 * 16 * 4096 * 4);
  float* kbuf  = (float*)take((size_t)2 * 16 * 4096 * 4);
  u16*   vt16  = (u16*)take((size_t)2 * 128 * 4096 * 2);
  float* rmax  = (float*)take((size_t)2 * 4096 * 4);
  float* rinv  = (float*)take((size_t)2 * 4096 * 4);
  float* sa1   = (float*)take((size_t)2 * 128 * 4096 * 4);
  float* sc1   = (float*)take((size_t)2 * 128 * 4096 * 4);
  float* energy = (float*)take((size_t)2 * 128 * 128 * 4);
  float* attn  = (float*)take((size_t)2 * 128 * 128 * 4);
  u16*   sa2   = (u16*)take((size_t)2 * 512 * 4096 * 2);
  u16*   sc2   = (u16*)take((size_t)2 * 512 * 4096 * 2);
  float* clsacc = (float*)take((size_t)3 * 2 * 5 * 4096 * 4);

  float* outF = (float*)d_out;
  float* outCls = outF + (size_t)2 * 512 * 4096;

  hipMemsetAsync(clsacc, 0, (size_t)3 * 2 * 5 * 4096 * 4, stream);

  k_prep_wv<<<64, 256, 0, stream>>>(pvw, wvT);
  k_prep_w<<<4608, 256, 0, stream>>>(convaw, convcw, Wb);
  k_bnrelu2<<<4096, 256, 0, stream>>>(x, bnaw, bnab, bnam, bnav,
                                      bncw, bncb, bncm, bncv, xa16, xcb16);
  k_conv3m<<<dim3(64, 4, 4), 256, 0, stream>>>(xa16, xcb16, Wb, sa0, sc0);
  k_qk<<<dim3(16, 32, 2), 256, 0, stream>>>(sa0, pqw, pqb, pkw, pkb, qb, kbuf);
  k_vt<<<dim3(16, 16, 2), 256, 0, stream>>>(sa0, wvT, pvb, vt16);
  k_pam_stats<<<dim3(1024, 2), 256, 0, stream>>>(qb, kbuf, rmax, rinv);
  k_pam_pv<<<dim3(256, 2), 256, 0, stream>>>(qb, kbuf, vt16, rmax, rinv, sa0, pgam, sa1);
  k_cam_energy<<<dim3(128, 2), 256, 0, stream>>>(sc0, energy);
  k_cam_softmax<<<dim3(128, 2), 64, 0, stream>>>(energy, attn);
  k_cam_out<<<dim3(16, 8, 2), 256, 0, stream>>>(sc0, attn, cgam, sc1);
  k_branch_out<<<dim3(16, 32, 4), 256, 0, stream>>>(sa1, sc1,
      bna1w, bna1b, bna1m, bna1v, bnc1w, bnc1b, bnc1m, bnc1v,
      conva1w, conva1b, convc1w, convc1b, sa2, sc2);
  k_heads<<<dim3(16, 2, 8), 256, 0, stream>>>(sa2, sc2, outfw, outaw, outcw, outF, clsacc);
  k_heads_final<<<480, 256, 0, stream>>>(clsacc, outfb, outab, outcb, outCls);
}

// Round 12
// 573.352 us; speedup vs baseline: 2.8686x; 1.0931x over previous
//
#include <hip/hip_runtime.h>

using u16 = unsigned short;
using short8 = __attribute__((ext_vector_type(8))) short;
using f32x4 = __attribute__((ext_vector_type(4))) float;

struct alignas(8) U16x4 { u16 x, y, z, w; };

__device__ __forceinline__ float bf2f(u16 u) {
  return __uint_as_float(((unsigned int)u) << 16);
}
__device__ __forceinline__ u16 f2bf(float f) {
  unsigned int u = __float_as_uint(f);
  unsigned int r = u + 0x7FFFu + ((u >> 16) & 1u);
  return (u16)(r >> 16);
}

// ---------------- K0a: transpose pam_v_w [c][ci] -> wvT [ci][c] --------------
__global__ void k_prep_wv(const float* __restrict__ wv, float* __restrict__ wvT) {
  int idx = blockIdx.x * 256 + threadIdx.x;   // 16384
  int ci = idx >> 7, c = idx & 127;
  wvT[ci * 128 + c] = wv[c * 128 + ci];
}

// ---------------- K0b: conv weights -> bf16, tap-major Wb[br][co][tap][ci] ---
__global__ void k_prep_w(const float* __restrict__ wa, const float* __restrict__ wc,
                         u16* __restrict__ Wb) {
  int idx = blockIdx.x * 256 + threadIdx.x;   // 2*128*9*512 = 1179648
  int ci = idx & 511;
  int rest = idx >> 9;
  int tap = rest % 9;
  int rest2 = rest / 9;
  int co = rest2 & 127, br = rest2 >> 7;
  const float* w = br ? wc : wa;
  Wb[idx] = f2bf(w[co * 4608 + ci * 9 + tap]);
}

// ---------------- K1: BN+ReLU for both branches, bf16 out --------------------
__global__ void k_bnrelu2(const float* __restrict__ x,
    const float* __restrict__ wa, const float* __restrict__ ba,
    const float* __restrict__ ma, const float* __restrict__ va,
    const float* __restrict__ wc, const float* __restrict__ bc,
    const float* __restrict__ mc, const float* __restrict__ vc,
    u16* __restrict__ xa16, u16* __restrict__ xcb16) {
  int i4 = (blockIdx.x * 256 + threadIdx.x) * 4;   // over 2*512*4096
  int c = (i4 >> 12) & 511;
  float sA = wa[c] * rsqrtf(va[c] + 1e-5f);
  float bA = ba[c] - ma[c] * sA;
  float sC = wc[c] * rsqrtf(vc[c] + 1e-5f);
  float bC = bc[c] - mc[c] * sC;
  float4 xv = *(const float4*)(x + i4);
  U16x4 oa, oc;
  oa.x = f2bf(fmaxf(xv.x * sA + bA, 0.f)); oc.x = f2bf(fmaxf(xv.x * sC + bC, 0.f));
  oa.y = f2bf(fmaxf(xv.y * sA + bA, 0.f)); oc.y = f2bf(fmaxf(xv.y * sC + bC, 0.f));
  oa.z = f2bf(fmaxf(xv.z * sA + bA, 0.f)); oc.z = f2bf(fmaxf(xv.z * sC + bC, 0.f));
  oa.w = f2bf(fmaxf(xv.w * sA + bA, 0.f)); oc.w = f2bf(fmaxf(xv.w * sC + bC, 0.f));
  *(U16x4*)(xa16 + i4) = oa;
  *(U16x4*)(xcb16 + i4) = oc;
}

// ---------------- K2: 3x3 conv via MFMA implicit GEMM ------------------------
__global__ __launch_bounds__(256) void k_conv3m(
    const u16* __restrict__ xa16, const u16* __restrict__ xcb16,
    const u16* __restrict__ Wb,
    float* __restrict__ sa0, float* __restrict__ sc0) {
  __shared__ u16 xl[64 * 40];   // [w][ci_l], stride 40 u16
  int t = threadIdx.x;
  int h = blockIdx.x;
  int co0 = blockIdx.y * 32;
  int z = blockIdx.z;
  int b = z & 1, br = z >> 1;
  const u16* xb = (br ? xcb16 : xa16) + ((size_t)b * 512 << 12);
  const short* wbase = (const short*)(Wb + (size_t)br * 128 * 9 * 512);
  float* out = br ? sc0 : sa0;

  int lane = t & 63, wave = t >> 6;
  int coh = (wave >> 1) << 4;
  int nh  = (wave & 1) << 5;
  int mi = lane & 15, quad = lane >> 4;

  int ws_ = t & 63;
  int cig = (t >> 6) << 3;

  f32x4 acc0 = {0.f, 0.f, 0.f, 0.f};
  f32x4 acc1 = {0.f, 0.f, 0.f, 0.f};

  const short* wrow = wbase + ((size_t)(co0 + coh + mi) * 9) * 512;

  for (int tap = 0; tap < 9; ++tap) {
    int dh = tap / 3 - 1, dw = tap % 3 - 1;
    int hh = h + dh;
    if (hh < 0 || hh > 63) continue;
    int wp = ws_ + dw;
    bool valid = (wp >= 0) && (wp < 64);
    const u16* srow = xb + (hh << 6) + wp;
    const short* wtap = wrow + (size_t)tap * 512;
    for (int ci0 = 0; ci0 < 512; ci0 += 32) {
      short8 v;
      const u16* sp = srow + ((size_t)(ci0 + cig) << 12);
#pragma unroll
      for (int j = 0; j < 8; ++j)
        v[j] = valid ? (short)sp[(size_t)j << 12] : (short)0;
      __syncthreads();
      *(short8*)(xl + ws_ * 40 + cig) = v;
      __syncthreads();
      short8 a = *(const short8*)(wtap + ci0 + quad * 8);
      short8 b0 = *(const short8*)(xl + (nh + mi) * 40 + quad * 8);
      short8 b1 = *(const short8*)(xl + (nh + 16 + mi) * 40 + quad * 8);
      acc0 = __builtin_amdgcn_mfma_f32_16x16x32_bf16(a, b0, acc0, 0, 0, 0);
      acc1 = __builtin_amdgcn_mfma_f32_16x16x32_bf16(a, b1, acc1, 0, 0, 0);
    }
  }
#pragma unroll
  for (int r = 0; r < 4; ++r) {
    int co = co0 + coh + quad * 4 + r;
    size_t o = ((size_t)(b * 128 + co) << 12) + (h << 6) + nh + mi;
    out[o] = acc0[r];
    out[o + 16] = acc1[r];
  }
}

// ---------------- K3a: 1x1 conv -> q,k ([b][16][4096] f32) -------------------
__global__ void k_qk(const float* __restrict__ sa0,
    const float* __restrict__ wq, const float* __restrict__ bq,
    const float* __restrict__ wk, const float* __restrict__ bk,
    float* __restrict__ qb, float* __restrict__ kb) {
  int n = blockIdx.x * 256 + threadIdx.x;
  int co = blockIdx.y, b = blockIdx.z;
  const float* w; float* dst; float bias;
  if (co < 16) { w = wq + co * 128; bias = bq[co]; dst = qb + ((b * 16 + co) << 12); }
  else { int c2 = co - 16; w = wk + c2 * 128; bias = bk[c2]; dst = kb + ((b * 16 + c2) << 12); }
  const float* s = sa0 + ((size_t)b * 128 << 12) + n;
  float acc = bias;
  for (int ci = 0; ci < 128; ++ci) acc = fmaf(w[ci], s[ci << 12], acc);
  dst[n] = acc;
}

// ---------------- K3b: 1x1 conv -> v, bf16, layout vt16[b][c][n] -------------
__global__ __launch_bounds__(256) void k_vt(const float* __restrict__ sa0,
    const float* __restrict__ wvT, const float* __restrict__ bv,
    u16* __restrict__ vt16) {
  int t = threadIdx.x;
  int n = blockIdx.x * 256 + t;
  int c0 = blockIdx.y * 8;
  int b = blockIdx.z;
  const float* s = sa0 + ((size_t)b * 128 << 12) + n;
  float acc[8];
#pragma unroll
  for (int c = 0; c < 8; ++c) acc[c] = bv[c0 + c];
  for (int ci = 0; ci < 128; ++ci) {
    float xv = s[ci << 12];
    const float* wp = wvT + ci * 128 + c0;
#pragma unroll
    for (int c = 0; c < 8; ++c) acc[c] = fmaf(wp[c], xv, acc[c]);
  }
#pragma unroll
  for (int c = 0; c < 8; ++c)
    vt16[((size_t)(b * 128 + c0 + c) << 12) + n] = f2bf(acc[c]);
}

// ---------------- K4: PAM softmax row stats (max, 1/sum), float4 K loads -----
__global__ __launch_bounds__(256) void k_pam_stats(const float* __restrict__ qb,
    const float* __restrict__ kb, float* __restrict__ rmax, float* __restrict__ rinv) {
  int t = threadIdx.x, lane = t & 63, wid = t >> 6;
  int b = blockIdx.y;
  int n = blockIdx.x * 4 + wid;
  float qreg[16];
  const float* qp = qb + ((size_t)b * 16 << 12) + n;
#pragma unroll
  for (int ch = 0; ch < 16; ++ch) qreg[ch] = qp[ch << 12];
  const float* kp = kb + ((size_t)b * 16 << 12);
  float mx = -1e30f, se = 0.f;
  for (int m4 = lane * 4; m4 < 4096; m4 += 256) {
    float e0 = 0.f, e1 = 0.f, e2 = 0.f, e3 = 0.f;
#pragma unroll
    for (int ch = 0; ch < 16; ++ch) {
      float4 kv = *(const float4*)(kp + (ch << 12) + m4);
      float qv = qreg[ch];
      e0 = fmaf(qv, kv.x, e0); e1 = fmaf(qv, kv.y, e1);
      e2 = fmaf(qv, kv.z, e2); e3 = fmaf(qv, kv.w, e3);
    }
#pragma unroll
    for (int j = 0; j < 4; ++j) {
      float e = j == 0 ? e0 : (j == 1 ? e1 : (j == 2 ? e2 : e3));
      float nm = fmaxf(mx, e);
      se = se * __expf(mx - nm) + __expf(e - nm);
      mx = nm;
    }
  }
#pragma unroll
  for (int off = 32; off >= 1; off >>= 1) {
    float om = __shfl_xor(mx, off);
    float os = __shfl_xor(se, off);
    float nm = fmaxf(mx, om);
    se = se * __expf(mx - nm) + os * __expf(om - nm);
    mx = nm;
  }
  if (lane == 0) { rmax[(b << 12) + n] = mx; rinv[(b << 12) + n] = 1.f / se; }
}

// ---------------- K5: PAM PV via MFMA, 16-n tile, split-m 2-way --------------
// 256 thr = 4 waves; wave w covers c in [32w, 32w+32); block does 2048 m.
__global__ __launch_bounds__(256) void k_pam_pv(const float* __restrict__ qb,
    const float* __restrict__ kb, const u16* __restrict__ vt16,
    const float* __restrict__ rmax, const float* __restrict__ rinv,
    const float* __restrict__ gamma, float* __restrict__ sa1) {
  __shared__ float qs[256];       // [ch][16 n]
  __shared__ float ks[1024];      // [ch][64 m]
  __shared__ u16 pL[16 * 72];     // [n][64 m] bf16, row stride 72 u16
  __shared__ float mxs[16], invs[16];
  __shared__ float obuf[128 * 17];
  int t = threadIdx.x;
  int b = blockIdx.y, n0 = blockIdx.x * 16;
  int mbeg = blockIdx.z * 2048, mend = mbeg + 2048;
  {
    int ch = t >> 4, r = t & 15;
    qs[t] = qb[((b * 16 + ch) << 12) + n0 + r];
  }
  if (t < 16) { mxs[t] = rmax[(b << 12) + n0 + t]; invs[t] = rinv[(b << 12) + n0 + t]; }
  int lane = t & 63, wave = t >> 6;
  int mi = lane & 15, quad = lane >> 4;
  int c0 = wave * 32;
  f32x4 acc0 = {0.f, 0.f, 0.f, 0.f};
  f32x4 acc1 = {0.f, 0.f, 0.f, 0.f};
  const float* kpb = kb + ((size_t)b * 16 << 12);
  const u16* vb = vt16 + ((size_t)b * 128 << 12);
  for (int idx = t; idx < 1024; idx += 256) {
    int ch = idx >> 6, mm = idx & 63;
    ks[idx] = kpb[(ch << 12) + mbeg + mm];
  }
  __syncthreads();
  int pn = t & 15, pmq = t >> 4;     // n, m-quad (m = pmq*4..+3)
  for (int m0 = mbeg; m0 < mend; m0 += 64) {
    // p-compute (n-major: one n, 4 consecutive m per thread -> b64 write)
    {
      float e0 = 0.f, e1 = 0.f, e2 = 0.f, e3 = 0.f;
#pragma unroll
      for (int ch = 0; ch < 16; ++ch) {
        float4 kv = *(const float4*)(ks + (ch << 6) + pmq * 4);
        float qv = qs[(ch << 4) + pn];
        e0 = fmaf(qv, kv.x, e0); e1 = fmaf(qv, kv.y, e1);
        e2 = fmaf(qv, kv.z, e2); e3 = fmaf(qv, kv.w, e3);
      }
      float mv = mxs[pn], iv = invs[pn];
      U16x4 pv4;
      pv4.x = f2bf(__expf(fminf(e0 - mv, 0.f)) * iv);
      pv4.y = f2bf(__expf(fminf(e1 - mv, 0.f)) * iv);
      pv4.z = f2bf(__expf(fminf(e2 - mv, 0.f)) * iv);
      pv4.w = f2bf(__expf(fminf(e3 - mv, 0.f)) * iv);
      *(U16x4*)(pL + pn * 72 + pmq * 4) = pv4;
    }
    __syncthreads();
    // stage next k tile (overlaps MFMA)
    if (m0 + 64 < mend) {
      int m1 = m0 + 64;
      for (int idx = t; idx < 1024; idx += 256) {
        int ch = idx >> 6, mm = idx & 63;
        ks[idx] = kpb[(ch << 12) + m1 + mm];
      }
    }
    // MFMA: acc[c][n] += vt16[c][m] * p[m][n]
#pragma unroll
    for (int kk = 0; kk < 64; kk += 32) {
      short8 bfrag = *(const short8*)(pL + mi * 72 + kk + quad * 8);
      const u16* ap = vb + ((size_t)(c0 + mi) << 12) + m0 + kk + quad * 8;
      short8 a0 = *(const short8*)ap;
      short8 a1 = *(const short8*)(ap + ((size_t)16 << 12));
      acc0 = __builtin_amdgcn_mfma_f32_16x16x32_bf16(a0, bfrag, acc0, 0, 0, 0);
      acc1 = __builtin_amdgcn_mfma_f32_16x16x32_bf16(a1, bfrag, acc1, 0, 0, 0);
    }
    __syncthreads();
  }
  // D layout: col(n)=lane&15, row=quad*4+r
#pragma unroll
  for (int r = 0; r < 4; ++r) {
    obuf[(c0 + quad * 4 + r) * 17 + mi] = acc0[r];
    obuf[(c0 + 16 + quad * 4 + r) * 17 + mi] = acc1[r];
  }
  __syncthreads();
  float g = gamma[0];
  for (int idx = t; idx < 2048; idx += 256) {
    int c = idx >> 4, nn = idx & 15;
    size_t o = ((size_t)(b * 128 + c) << 12) + n0 + nn;
    atomicAdd(&sa1[o], g * obuf[c * 17 + nn]);
  }
}

// ---------------- K6a: CAM Gram energy, block per row c, all threads ---------
__global__ __launch_bounds__(256) void k_cam_energy(const float* __restrict__ f,
                                                    float* __restrict__ energy) {
  __shared__ float fc[4096];
  __shared__ float part[256];
  int t = threadIdx.x;
  int c = blockIdx.x, b = blockIdx.y;
  const float* fr = f + ((size_t)(b * 128 + c) << 12);
  for (int i = t; i < 4096; i += 256) fc[i] = fr[i];
  __syncthreads();
  int d = t & 127, seg = t >> 7;
  const float* fd = f + ((size_t)(b * 128 + d) << 12) + seg * 2048;
  const float* fcs = fc + seg * 2048;
  float acc = 0.f;
  for (int nn = 0; nn < 2048; ++nn) acc = fmaf(fcs[nn], fd[nn], acc);
  part[t] = acc;
  __syncthreads();
  if (t < 128)
    energy[((b * 128 + c) << 7) + t] = part[t] + part[t + 128];
}

// ---------------- K6b: CAM softmax row (attn = softmax(rowmax - e)) ----------
__global__ void k_cam_softmax(const float* __restrict__ energy, float* __restrict__ attn) {
  int lane = threadIdx.x;   // 64
  int c = blockIdx.x, b = blockIdx.y;
  const float* e = energy + ((b * 128 + c) << 7);
  float e0 = e[lane], e1 = e[lane + 64];
  float mn = fminf(e0, e1);
#pragma unroll
  for (int off = 32; off >= 1; off >>= 1) mn = fminf(mn, __shfl_xor(mn, off));
  float p0 = __expf(fminf(mn - e0, 0.f)), p1 = __expf(fminf(mn - e1, 0.f));
  float s = p0 + p1;
#pragma unroll
  for (int off = 32; off >= 1; off >>= 1) s += __shfl_xor(s, off);
  float inv = 1.f / s;
  float* a = attn + ((b * 128 + c) << 7);
  a[lane] = p0 * inv;
  a[lane + 64] = p1 * inv;
}

// ---------------- K7: CAM out + residual -------------------------------------
__global__ __launch_bounds__(256) void k_cam_out(const float* __restrict__ f,
    const float* __restrict__ attn, const float* __restrict__ gamma,
    float* __restrict__ sc1) {
  __shared__ float at2[128 * 16];
  int t = threadIdx.x;
  int b = blockIdx.z, c0 = blockIdx.y * 16;
  int n = blockIdx.x * 256 + t;
  for (int idx = t; idx < 2048; idx += 256) {
    int d = idx >> 4, cc = idx & 15;
    at2[idx] = attn[((b * 128 + c0 + cc) << 7) + d];
  }
  __syncthreads();
  float acc[16] = {};
  const float* fb = f + ((size_t)b * 128 << 12) + n;
  for (int d = 0; d < 128; ++d) {
    float fv = fb[d << 12];
    const float* ap = at2 + d * 16;
#pragma unroll
    for (int cc = 0; cc < 16; ++cc) acc[cc] = fmaf(ap[cc], fv, acc[cc]);
  }
  float g = gamma[0];
#pragma unroll
  for (int cc = 0; cc < 16; ++cc) {
    size_t o = ((size_t)(b * 128 + c0 + cc) << 12) + n;
    sc1[o] = fmaf(g, acc[cc], f[o]);
  }
}

// ---------------- K8: BN+ReLU + 1x1 conv 128->512, 16 co per block -----------
__global__ __launch_bounds__(256) void k_branch_out(
    const float* __restrict__ sa1, const float* __restrict__ sc1,
    const float* __restrict__ wa_, const float* __restrict__ ba_,
    const float* __restrict__ ma_, const float* __restrict__ va_,
    const float* __restrict__ wc_, const float* __restrict__ bc_,
    const float* __restrict__ mc_, const float* __restrict__ vc_,
    const float* __restrict__ Wa, const float* __restrict__ Ba,
    const float* __restrict__ Wc, const float* __restrict__ Bc,
    u16* __restrict__ sa2, u16* __restrict__ sc2) {
  int z = blockIdx.z;
  int b = z & 1, br = z >> 1;
  const float* src = br ? sc1 : sa1;
  const float* bw = br ? wc_ : wa_;
  const float* bb = br ? bc_ : ba_;
  const float* bm = br ? mc_ : ma_;
  const float* bvv = br ? vc_ : va_;
  const float* W = br ? Wc : Wa;
  const float* Bs = br ? Bc : Ba;
  u16* dst = br ? sc2 : sa2;
  __shared__ float wl[128 * 16];
  __shared__ float scl[128], shf[128];
  int t = threadIdx.x;
  int co0 = blockIdx.y * 16;
  int n = blockIdx.x * 256 + t;
  if (t < 128) {
    float s = bw[t] * rsqrtf(bvv[t] + 1e-5f);
    scl[t] = s;
    shf[t] = bb[t] - bm[t] * s;
  }
  for (int idx = t; idx < 2048; idx += 256) {
    int ci = idx >> 4, cc = idx & 15;
    wl[idx] = W[(co0 + cc) * 128 + ci];
  }
  __syncthreads();
  float acc[16] = {};
  const float* sp = src + ((size_t)b * 128 << 12) + n;
  for (int ci = 0; ci < 128; ++ci) {
    float xv = fmaxf(fmaf(sp[ci << 12], scl[ci], shf[ci]), 0.f);
    const float* wp = wl + ci * 16;
    float4 w0 = *(const float4*)wp;
    float4 w1 = *(const float4*)(wp + 4);
    float4 w2 = *(const float4*)(wp + 8);
    float4 w3 = *(const float4*)(wp + 12);
    acc[0] = fmaf(w0.x, xv, acc[0]);  acc[1] = fmaf(w0.y, xv, acc[1]);
    acc[2] = fmaf(w0.z, xv, acc[2]);  acc[3] = fmaf(w0.w, xv, acc[3]);
    acc[4] = fmaf(w1.x, xv, acc[4]);  acc[5] = fmaf(w1.y, xv, acc[5]);
    acc[6] = fmaf(w1.z, xv, acc[6]);  acc[7] = fmaf(w1.w, xv, acc[7]);
    acc[8] = fmaf(w2.x, xv, acc[8]);  acc[9] = fmaf(w2.y, xv, acc[9]);
    acc[10] = fmaf(w2.z, xv, acc[10]); acc[11] = fmaf(w2.w, xv, acc[11]);
    acc[12] = fmaf(w3.x, xv, acc[12]); acc[13] = fmaf(w3.y, xv, acc[13]);
    acc[14] = fmaf(w3.z, xv, acc[14]); acc[15] = fmaf(w3.w, xv, acc[15]);
  }
#pragma unroll
  for (int cc = 0; cc < 16; ++cc) {
    dst[((size_t)(b * 512 + co0 + cc) << 12) + n] = f2bf(acc[cc] + Bs[co0 + cc]);
  }
}

// ---------------- K9a: fusion + partial class-head sums (8-way c split) ------
__global__ __launch_bounds__(256) void k_heads(const u16* __restrict__ sa2,
    const u16* __restrict__ sc2,
    const float* __restrict__ wf, const float* __restrict__ wa, const float* __restrict__ wc,
    float* __restrict__ outFusion, float* __restrict__ clsacc) {
  __shared__ float lw[3 * 5 * 64];
  int t = threadIdx.x;
  int b = blockIdx.y, co0 = blockIdx.z * 64;
  int n = blockIdx.x * 256 + t;
  for (int idx = t; idx < 960; idx += 256) {
    int arr = idx / 320, rest = idx - arr * 320;
    int cls = rest >> 6, cc = rest & 63;
    const float* w = arr == 0 ? wf : (arr == 1 ? wa : wc);
    lw[idx] = w[cls * 512 + co0 + cc];
  }
  __syncthreads();
  float af[5] = {}, aa[5] = {}, ac[5] = {};
  for (int cc = 0; cc < 64; ++cc) {
    size_t o = ((size_t)(b * 512 + co0 + cc) << 12) + n;
    float a = bf2f(sa2[o]), c = bf2f(sc2[o]);
    float s = a + c;
    outFusion[o] = s;
#pragma unroll
    for (int cls = 0; cls < 5; ++cls) {
      af[cls] = fmaf(lw[0 * 320 + cls * 64 + cc], s, af[cls]);
      aa[cls] = fmaf(lw[1 * 320 + cls * 64 + cc], a, aa[cls]);
      ac[cls] = fmaf(lw[2 * 320 + cls * 64 + cc], c, ac[cls]);
    }
  }
#pragma unroll
  for (int cls = 0; cls < 5; ++cls) {
    int o = ((b * 5 + cls) << 12) + n;
    atomicAdd(&clsacc[o], af[cls]);
    atomicAdd(&clsacc[40960 + o], aa[cls]);
    atomicAdd(&clsacc[81920 + o], ac[cls]);
  }
}

// ---------------- K9b: add bias, f32 out -------------------------------------
__global__ void k_heads_final(const float* __restrict__ clsacc,
    const float* __restrict__ bf_, const float* __restrict__ ba_,
    const float* __restrict__ bc_, float* __restrict__ outCls) {
  int idx = blockIdx.x * 256 + threadIdx.x;   // 122880
  int arr = idx / 40960;
  int rest = idx - arr * 40960;
  int cls = (rest >> 12) % 5;
  const float* bp = arr == 0 ? bf_ : (arr == 1 ? ba_ : bc_);
  outCls[idx] = clsacc[idx] + bp[cls];
}

extern "C" void kernel_launch(void* const* d_in, const int* in_sizes, int n_in,
                              void* d_out, int out_size, void* d_ws, size_t ws_size,
                              hipStream_t stream) {
  (void)in_sizes; (void)n_in; (void)out_size; (void)ws_size;
  const float* x      = (const float*)d_in[0];
  const float* bnaw   = (const float*)d_in[1];
  const float* bnab   = (const float*)d_in[2];
  const float* bnam   = (const float*)d_in[3];
  const float* bnav   = (const float*)d_in[4];
  const float* convaw = (const float*)d_in[5];
  const float* bncw   = (const float*)d_in[6];
  const float* bncb   = (const float*)d_in[7];
  const float* bncm   = (const float*)d_in[8];
  const float* bncv   = (const float*)d_in[9];
  const float* convcw = (const float*)d_in[10];
  const float* pqw    = (const float*)d_in[11];
  const float* pqb    = (const float*)d_in[12];
  const float* pkw    = (const float*)d_in[13];
  const float* pkb    = (const float*)d_in[14];
  const float* pvw    = (const float*)d_in[15];
  const float* pvb    = (const float*)d_in[16];
  const float* pgam   = (const float*)d_in[17];
  const float* cgam   = (const float*)d_in[18];
  const float* bna1w  = (const float*)d_in[19];
  const float* bna1b  = (const float*)d_in[20];
  const float* bna1m  = (const float*)d_in[21];
  const float* bna1v  = (const float*)d_in[22];
  const float* conva1w = (const float*)d_in[23];
  const float* conva1b = (const float*)d_in[24];
  const float* bnc1w  = (const float*)d_in[25];
  const float* bnc1b  = (const float*)d_in[26];
  const float* bnc1m  = (const float*)d_in[27];
  const float* bnc1v  = (const float*)d_in[28];
  const float* convc1w = (const float*)d_in[29];
  const float* convc1b = (const float*)d_in[30];
  const float* outaw  = (const float*)d_in[31];
  const float* outab  = (const float*)d_in[32];
  const float* outcw  = (const float*)d_in[33];
  const float* outcb  = (const float*)d_in[34];
  const float* outfw  = (const float*)d_in[35];
  const float* outfb  = (const float*)d_in[36];

  char* wsb = (char*)d_ws;
  size_t off = 0;
  auto take = [&](size_t bytes) -> void* {
    void* p = wsb + off;
    off += (bytes + 255) & ~(size_t)255;
    return p;
  };
  float* wvT   = (float*)take((size_t)128 * 128 * 4);
  u16*   Wb    = (u16*)take((size_t)2 * 128 * 9 * 512 * 2);
  u16*   xa16  = (u16*)take((size_t)2 * 512 * 4096 * 2);
  u16*   xcb16 = (u16*)take((size_t)2 * 512 * 4096 * 2);
  float* sa0   = (float*)take((size_t)2 * 128 * 4096 * 4);
  float* sc0   = (float*)take((size_t)2 * 128 * 4096 * 4);
  float* qb    = (float*)take((size_t)2 * 16 * 4096 * 4);
  float* kbuf  = (float*)take((size_t)2 * 16 * 4096 * 4);
  u16*   vt16  = (u16*)take((size_t)2 * 128 * 4096 * 2);
  float* rmax  = (float*)take((size_t)2 * 4096 * 4);
  float* rinv  = (float*)take((size_t)2 * 4096 * 4);
  float* sa1   = (float*)take((size_t)2 * 128 * 4096 * 4);
  float* sc1   = (float*)take((size_t)2 * 128 * 4096 * 4);
  float* energy = (float*)take((size_t)2 * 128 * 128 * 4);
  float* attn  = (float*)take((size_t)2 * 128 * 128 * 4);
  u16*   sa2   = (u16*)take((size_t)2 * 512 * 4096 * 2);
  u16*   sc2   = (u16*)take((size_t)2 * 512 * 4096 * 2);
  float* clsacc = (float*)take((size_t)3 * 2 * 5 * 4096 * 4);

  float* outF = (float*)d_out;
  float* outCls = outF + (size_t)2 * 512 * 4096;

  hipMemsetAsync(clsacc, 0, (size_t)3 * 2 * 5 * 4096 * 4, stream);

  k_prep_wv<<<64, 256, 0, stream>>>(pvw, wvT);
  k_prep_w<<<4608, 256, 0, stream>>>(convaw, convcw, Wb);
  k_bnrelu2<<<4096, 256, 0, stream>>>(x, bnaw, bnab, bnam, bnav,
                                      bncw, bncb, bncm, bncv, xa16, xcb16);
  k_conv3m<<<dim3(64, 4, 4), 256, 0, stream>>>(xa16, xcb16, Wb, sa0, sc0);
  k_qk<<<dim3(16, 32, 2), 256, 0, stream>>>(sa0, pqw, pqb, pkw, pkb, qb, kbuf);
  k_vt<<<dim3(16, 16, 2), 256, 0, stream>>>(sa0, wvT, pvb, vt16);
  k_pam_stats<<<dim3(1024, 2), 256, 0, stream>>>(qb, kbuf, rmax, rinv);
  // sa1 = sa0 (residual base), then pam_pv atomically adds gamma * (V @ attn^T)
  hipMemcpyAsync(sa1, sa0, (size_t)2 * 128 * 4096 * 4, hipMemcpyDeviceToDevice, stream);
  k_pam_pv<<<dim3(256, 2, 2), 256, 0, stream>>>(qb, kbuf, vt16, rmax, rinv, pgam, sa1);
  k_cam_energy<<<dim3(128, 2), 256, 0, stream>>>(sc0, energy);
  k_cam_softmax<<<dim3(128, 2), 64, 0, stream>>>(energy, attn);
  k_cam_out<<<dim3(16, 8, 2), 256, 0, stream>>>(sc0, attn, cgam, sc1);
  k_branch_out<<<dim3(16, 32, 4), 256, 0, stream>>>(sa1, sc1,
      bna1w, bna1b, bna1m, bna1v, bnc1w, bnc1b, bnc1m, bnc1v,
      conva1w, conva1b, convc1w, convc1b, sa2, sc2);
  k_heads<<<dim3(16, 2, 8), 256, 0, stream>>>(sa2, sc2, outfw, outaw, outcw, outF, clsacc);
  k_heads_final<<<480, 256, 0, stream>>>(clsacc, outfb, outab, outcb, outCls);
}